// Round 6
// baseline (1636.995 us; speedup 1.0000x reference)
//
#include <hip/hip_runtime.h>

// ---------------------------------------------------------------------------
// DimeNet++ interaction block, round 5: fused GEMM chains + permuted E1 stream.
//   E = 300000, T = 3000000, D = 128, D_DOWN = 64.
// Pipeline:
//   rbf1:   re1 = rbf@w_rbf1                                   [E,8]
//   count/scan: CSR offsets of idx_ji
//   e1fill: per triplet t: e1 = sbf[t]@w_sbf1; pos=cursor[ji]++;
//           E1p[pos]=e1; kjp[pos]=idx_kj[t]
//   K1:     W3 = silu( (silu(x@w_kj+b_kj) * (re1@w_rbf2)) @ w_down )   (fused)
//   gather: W4[e] = sum_j (E1p[j]·w2col) * W3[kjp[j]]          (sequential)
//   K4:     h0 = silu(x@w_ji+b_ji) + silu(W4@w_up)             (fused)
//   K5:     OUT = silu(res1(h0)@w_bs+b_bs) + x                 (3 GEMMs fused)
//   K6/K7:  OUT = OUT + silu(silu(OUT@w1+b1)@w2+b2)            (in-place, fused)
// All GEMMs: split-bf16 hi/lo 3-pass MFMA (fp32 quality); inner activations
// bounce through a fp32 LDS tile (never written to HBM).
// ---------------------------------------------------------------------------

typedef __attribute__((ext_vector_type(8))) short bf16x8;
typedef __attribute__((ext_vector_type(4))) float f32x4;

__device__ __forceinline__ float silu_f(float v) { return v / (1.0f + __expf(-v)); }
__device__ __forceinline__ short f2bf(float f) {
    unsigned u = __float_as_uint(f);
    unsigned r = u + 0x7fffu + ((u >> 16) & 1u);
    return (short)(r >> 16);
}
__device__ __forceinline__ float bf2f(short s) {
    return __uint_as_float(((unsigned)(unsigned short)s) << 16);
}
__device__ __forceinline__ void split8(const float* v, bf16x8& ah, bf16x8& al) {
    #pragma unroll
    for (int j = 0; j < 8; ++j) { short h = f2bf(v[j]); ah[j] = h; al[j] = f2bf(v[j] - bf2f(h)); }
}

// stage W[K][N] fp32 -> wslot bf16 hi/lo, transposed + chunk-swizzled (512 thr)
template<int K, int N>
__device__ __forceinline__ void stage_w(const float* __restrict__ W, short* wslot, int tid) {
    constexpr int SEG = 512 / N, KPS = K / SEG, SM = K / 8 - 1, CH = K / 8;
    const int col = tid % N, seg = tid / N;
    #pragma unroll
    for (int j = 0; j < KPS; j += 8) {
        const int kb = seg * KPS + j;
        float v[8];
        #pragma unroll
        for (int jj = 0; jj < 8; ++jj) v[jj] = W[(size_t)(kb + jj) * N + col];
        bf16x8 ah, al; split8(v, ah, al);
        const int sh = (kb >> 3) ^ (col & SM);
        *(bf16x8*)&wslot[col * 2 * K + (sh << 3)]        = ah;
        *(bf16x8*)&wslot[col * 2 * K + ((CH + sh) << 3)] = al;
    }
}

// one 32-wide k-step, 3-pass split MFMA over NF column-frags
template<int K, int N, int NF>
__device__ __forceinline__ void mfma_step(const bf16x8& ah, const bf16x8& al,
                                          const short* wslot, int k0, int acol, f32x4* acc) {
    constexpr int SM = K / 8 - 1, CH = K / 8;
    const int sh = (k0 >> 3) ^ (acol & SM);
    #pragma unroll
    for (int n = 0; n < NF; ++n) {
        const int col = n * 16 + acol;
        const bf16x8 bh = *(const bf16x8*)&wslot[col * 2 * K + (sh << 3)];
        const bf16x8 bl = *(const bf16x8*)&wslot[col * 2 * K + ((CH + sh) << 3)];
        acc[n] = __builtin_amdgcn_mfma_f32_16x16x32_bf16(ah, bh, acc[n], 0, 0, 0);
        acc[n] = __builtin_amdgcn_mfma_f32_16x16x32_bf16(al, bh, acc[n], 0, 0, 0);
        acc[n] = __builtin_amdgcn_mfma_f32_16x16x32_bf16(ah, bl, acc[n], 0, 0, 0);
    }
}

#define TPITCH 132   // t_lds row pitch in floats (128 + 4 pad; keeps 16B align)

// ---------------- small prologue kernels ------------------------------------

__global__ void rbf1_kernel(const float* __restrict__ rbf, const float* __restrict__ w_rbf1,
                            float* __restrict__ re1, int E) {
    const int i = blockIdx.x * 256 + threadIdx.x;
    const int e = i >> 3, p = i & 7;
    if (e < E) {
        float s = 0.f;
        #pragma unroll
        for (int q = 0; q < 6; ++q) s = fmaf(rbf[e * 6 + q], w_rbf1[q * 8 + p], s);
        re1[i] = s;
    }
}

__global__ void count_kernel(const int* __restrict__ idx_ji, int* __restrict__ cnt, int T) {
    const int t = blockIdx.x * 256 + threadIdx.x;
    if (t < T) atomicAdd(&cnt[idx_ji[t]], 1);
}

__global__ void scan_partial_kernel(const int* __restrict__ cnt, int* __restrict__ partial, int E) {
    __shared__ int red[256];
    const int tid = threadIdx.x;
    const int base = blockIdx.x * 1024 + tid * 4;
    int s = 0;
    #pragma unroll
    for (int i = 0; i < 4; ++i) { const int g = base + i; if (g < E) s += cnt[g]; }
    red[tid] = s;
    __syncthreads();
    for (int off = 128; off > 0; off >>= 1) {
        if (tid < off) red[tid] += red[tid + off];
        __syncthreads();
    }
    if (tid == 0) partial[blockIdx.x] = red[0];
}

__global__ void scan_block_kernel(const int* __restrict__ partial, int* __restrict__ blockoff,
                                  int NB, int* offsets, int E) {
    __shared__ int red[256];
    const int tid = threadIdx.x;
    int v[4]; int s = 0;
    #pragma unroll
    for (int i = 0; i < 4; ++i) { const int g = tid * 4 + i; v[i] = (g < NB) ? partial[g] : 0; s += v[i]; }
    red[tid] = s;
    __syncthreads();
    for (int off = 1; off < 256; off <<= 1) {
        const int add = (tid >= off) ? red[tid - off] : 0;
        __syncthreads();
        red[tid] += add;
        __syncthreads();
    }
    int excl = (tid == 0) ? 0 : red[tid - 1];
    #pragma unroll
    for (int i = 0; i < 4; ++i) { const int g = tid * 4 + i; if (g < NB) blockoff[g] = excl; excl += v[i]; }
    if (tid == 255) offsets[E] = red[255];
}

__global__ void scan_final_kernel(const int* cnt, const int* __restrict__ blockoff,
                                  int* offsets, int* cursor, int E) {
    __shared__ int red[256];
    const int tid = threadIdx.x;
    const int base = blockIdx.x * 1024 + tid * 4;
    int v[4]; int s = 0;
    #pragma unroll
    for (int i = 0; i < 4; ++i) { const int g = base + i; v[i] = (g < E) ? cnt[g] : 0; s += v[i]; }
    red[tid] = s;
    __syncthreads();
    for (int off = 1; off < 256; off <<= 1) {
        const int add = (tid >= off) ? red[tid - off] : 0;
        __syncthreads();
        red[tid] += add;
        __syncthreads();
    }
    int run = blockoff[blockIdx.x] + ((tid == 0) ? 0 : red[tid - 1]);
    #pragma unroll
    for (int i = 0; i < 4; ++i) {
        const int g = base + i;
        if (g < E) { offsets[g] = run; cursor[g] = run; }
        run += v[i];
    }
}

// e1 projection fused with CSR fill: E1p/kjp land at CSR position
__launch_bounds__(256, 4)
__global__ void e1fill_kernel(const float* __restrict__ sbf, const float* __restrict__ w_sbf1,
                              const int* __restrict__ idx_ji, const int* __restrict__ idx_kj,
                              int* __restrict__ cursor,
                              float* __restrict__ E1p, int* __restrict__ kjp, int T) {
    const int t = blockIdx.x * 256 + threadIdx.x;
    if (t >= T) return;
    const float* srow = sbf + (size_t)t * 42;
    float e1[8] = {0.f, 0.f, 0.f, 0.f, 0.f, 0.f, 0.f, 0.f};
    #pragma unroll
    for (int q = 0; q < 42; q += 2) {
        const float2 sv = *(const float2*)&srow[q];
        #pragma unroll
        for (int p = 0; p < 8; ++p) {
            e1[p] = fmaf(sv.x, w_sbf1[q * 8 + p], e1[p]);
            e1[p] = fmaf(sv.y, w_sbf1[(q + 1) * 8 + p], e1[p]);
        }
    }
    const int pos = atomicAdd(&cursor[idx_ji[t]], 1);
    *(float4*)&E1p[(size_t)pos * 8]     = *(float4*)&e1[0];
    *(float4*)&E1p[(size_t)pos * 8 + 4] = *(float4*)&e1[4];
    kjp[pos] = idx_kj[t];
}

// ---------------- gather: sequential E1p/kjp streams -------------------------
__launch_bounds__(256, 4)
__global__ void gather_kernel(const float* __restrict__ E1p,     // [T, 8] permuted
                              const int* __restrict__ kjp,       // [T]    permuted
                              const float* __restrict__ w_sbf2,  // [8, 64]
                              const int* __restrict__ offsets,   // [E+1]
                              const float* __restrict__ xkjd,    // [E, 64]
                              float* __restrict__ agg,           // [E, 64]
                              int E)
{
    const int tid  = threadIdx.x;
    const int lane = tid & 63;
    const int e    = blockIdx.x * 4 + (tid >> 6);

    float w2[8];
    #pragma unroll
    for (int p = 0; p < 8; ++p) w2[p] = w_sbf2[p * 64 + lane];

    if (e >= E) return;
    const int j0 = __builtin_amdgcn_readfirstlane(offsets[e]);
    const int j1 = __builtin_amdgcn_readfirstlane(offsets[e + 1]);

    float acc = 0.f;
    if (j0 < j1) {
        int kj = __builtin_amdgcn_readfirstlane(kjp[j0]);
        float4 ea = *(const float4*)&E1p[(size_t)j0 * 8];
        float4 eb = *(const float4*)&E1p[(size_t)j0 * 8 + 4];
        for (int j = j0; j < j1; ++j) {
            const float xv = xkjd[(size_t)kj * 64 + lane];   // issue early
            int kn = 0; float4 ean = {}, ebn = {};
            if (j + 1 < j1) {
                kn  = __builtin_amdgcn_readfirstlane(kjp[j + 1]);
                ean = *(const float4*)&E1p[(size_t)(j + 1) * 8];
                ebn = *(const float4*)&E1p[(size_t)(j + 1) * 8 + 4];
            }
            float sv = ea.x * w2[0];
            sv = fmaf(ea.y, w2[1], sv);
            sv = fmaf(ea.z, w2[2], sv);
            sv = fmaf(ea.w, w2[3], sv);
            sv = fmaf(eb.x, w2[4], sv);
            sv = fmaf(eb.y, w2[5], sv);
            sv = fmaf(eb.z, w2[6], sv);
            sv = fmaf(eb.w, w2[7], sv);
            acc = fmaf(xv, sv, acc);
            kj = kn; ea = ean; eb = ebn;
        }
    }
    agg[(size_t)e * 64 + lane] = acc;
}

// ---------------- K1: W3 = silu((silu(x@w_kj+b)*rbf_e)@w_down) --------------
__launch_bounds__(512, 1)
__global__ void k1_kernel(const float* __restrict__ x, const float* __restrict__ w_kj,
                          const float* __restrict__ b_kj, const float* __restrict__ re1,
                          const float* __restrict__ w_rbf2, const float* __restrict__ w_down,
                          float* __restrict__ W3, int E)
{
    __shared__ __align__(16) short wslot[128 * 2 * 128];
    __shared__ __align__(16) float t_lds[128 * TPITCH];
    __shared__ float w2_lds[8 * 128];
    const int tid = threadIdx.x, lane = tid & 63, wid = tid >> 6;
    const int row0 = blockIdx.x * 128 + wid * 16;
    const int acol = lane & 15, kq = lane >> 4;

    const int arow = row0 + acol;
    const bool av = arow < E;
    const float* xr = x + (size_t)arow * 128;
    float va[4][8];
    #pragma unroll
    for (int ks = 0; ks < 4; ++ks) {
        #pragma unroll
        for (int jj = 0; jj < 8; ++jj) va[ks][jj] = 0.f;
        if (av) {
            const int k0 = ks * 32 + kq * 8;
            *(float4*)&va[ks][0] = *(const float4*)&xr[k0];
            *(float4*)&va[ks][4] = *(const float4*)&xr[k0 + 4];
        }
    }
    stage_w<128, 128>(w_kj, wslot, tid);
    for (int i = tid; i < 1024; i += 512) w2_lds[i] = w_rbf2[i];
    __syncthreads();

    f32x4 acc[8];
    #pragma unroll
    for (int n = 0; n < 8; ++n)
        #pragma unroll
        for (int i = 0; i < 4; ++i) acc[n][i] = 0.f;
    #pragma unroll
    for (int ks = 0; ks < 4; ++ks) {
        bf16x8 ah, al; split8(va[ks], ah, al);
        mfma_step<128, 128, 8>(ah, al, wslot, ks * 32 + kq * 8, acol, acc);
    }

    // epilogue 1: u = silu(acc+b)*rbf_e -> t_lds
    float e1r[4][8];
    #pragma unroll
    for (int r = 0; r < 4; ++r) {
        const int ge = row0 + kq * 4 + r;
        if (ge < E) {
            *(float4*)&e1r[r][0] = *(const float4*)&re1[(size_t)ge * 8];
            *(float4*)&e1r[r][4] = *(const float4*)&re1[(size_t)ge * 8 + 4];
        } else {
            #pragma unroll
            for (int p = 0; p < 8; ++p) e1r[r][p] = 0.f;
        }
    }
    #pragma unroll
    for (int n = 0; n < 8; ++n) {
        const int col = n * 16 + acol;
        const float bv = b_kj[col];
        float w2c[8];
        #pragma unroll
        for (int p = 0; p < 8; ++p) w2c[p] = w2_lds[p * 128 + col];
        #pragma unroll
        for (int r = 0; r < 4; ++r) {
            float s = 0.f;
            #pragma unroll
            for (int p = 0; p < 8; ++p) s = fmaf(e1r[r][p], w2c[p], s);
            t_lds[(wid * 16 + kq * 4 + r) * TPITCH + col] = silu_f(acc[n][r] + bv) * s;
        }
    }
    __syncthreads();                    // wslot reads + t writes complete
    stage_w<128, 64>(w_down, wslot, tid);
    __syncthreads();

    f32x4 acc2[4];
    #pragma unroll
    for (int n = 0; n < 4; ++n)
        #pragma unroll
        for (int i = 0; i < 4; ++i) acc2[n][i] = 0.f;
    const float* trow = &t_lds[(wid * 16 + acol) * TPITCH];
    #pragma unroll
    for (int ks = 0; ks < 4; ++ks) {
        float v[8];
        const int k0 = ks * 32 + kq * 8;
        *(float4*)&v[0] = *(const float4*)&trow[k0];
        *(float4*)&v[4] = *(const float4*)&trow[k0 + 4];
        bf16x8 ah, al; split8(v, ah, al);
        mfma_step<128, 64, 4>(ah, al, wslot, k0, acol, acc2);
    }
    #pragma unroll
    for (int n = 0; n < 4; ++n) {
        const int col = n * 16 + acol;
        #pragma unroll
        for (int r = 0; r < 4; ++r) {
            const int ge = row0 + kq * 4 + r;
            if (ge < E) W3[(size_t)ge * 64 + col] = silu_f(acc2[n][r]);
        }
    }
}

// ---------------- K4: h0 = silu(x@w_ji+b_ji) + silu(W4@w_up) ----------------
__launch_bounds__(512, 1)
__global__ void k4_kernel(const float* __restrict__ x, const float* __restrict__ w_ji,
                          const float* __restrict__ b_ji, const float* __restrict__ W4,
                          const float* __restrict__ w_up, float* __restrict__ h0, int E)
{
    __shared__ __align__(16) short wslot[128 * 2 * 128];
    const int tid = threadIdx.x, lane = tid & 63, wid = tid >> 6;
    const int row0 = blockIdx.x * 128 + wid * 16;
    const int acol = lane & 15, kq = lane >> 4;

    const int arow = row0 + acol;
    const bool av = arow < E;
    const float* xr = x + (size_t)arow * 128;
    const float* wr = W4 + (size_t)arow * 64;
    float va[4][8], vb[2][8];
    #pragma unroll
    for (int ks = 0; ks < 4; ++ks) {
        #pragma unroll
        for (int jj = 0; jj < 8; ++jj) va[ks][jj] = 0.f;
        if (av) {
            const int k0 = ks * 32 + kq * 8;
            *(float4*)&va[ks][0] = *(const float4*)&xr[k0];
            *(float4*)&va[ks][4] = *(const float4*)&xr[k0 + 4];
        }
    }
    #pragma unroll
    for (int ks = 0; ks < 2; ++ks) {
        #pragma unroll
        for (int jj = 0; jj < 8; ++jj) vb[ks][jj] = 0.f;
        if (av) {
            const int k0 = ks * 32 + kq * 8;
            *(float4*)&vb[ks][0] = *(const float4*)&wr[k0];
            *(float4*)&vb[ks][4] = *(const float4*)&wr[k0 + 4];
        }
    }
    stage_w<128, 128>(w_ji, wslot, tid);
    __syncthreads();

    f32x4 acc1[8], acc2[8];
    #pragma unroll
    for (int n = 0; n < 8; ++n)
        #pragma unroll
        for (int i = 0; i < 4; ++i) { acc1[n][i] = 0.f; acc2[n][i] = 0.f; }
    #pragma unroll
    for (int ks = 0; ks < 4; ++ks) {
        bf16x8 ah, al; split8(va[ks], ah, al);
        mfma_step<128, 128, 8>(ah, al, wslot, ks * 32 + kq * 8, acol, acc1);
    }
    __syncthreads();                    // wslot reads complete
    stage_w<64, 128>(w_up, wslot, tid);
    __syncthreads();
    #pragma unroll
    for (int ks = 0; ks < 2; ++ks) {
        bf16x8 ah, al; split8(vb[ks], ah, al);
        mfma_step<64, 128, 8>(ah, al, wslot, ks * 32 + kq * 8, acol, acc2);
    }
    #pragma unroll
    for (int n = 0; n < 8; ++n) {
        const int col = n * 16 + acol;
        const float bv = b_ji[col];
        #pragma unroll
        for (int r = 0; r < 4; ++r) {
            const int ge = row0 + kq * 4 + r;
            if (ge < E)
                h0[(size_t)ge * 128 + col] = silu_f(acc1[n][r] + bv) + silu_f(acc2[n][r]);
        }
    }
}

// ---------------- K5: OUT = silu(res1(h0)@w_bs+b_bs) + x --------------------
__launch_bounds__(512, 1)
__global__ void k5_kernel(const float* __restrict__ h0, const float* __restrict__ x,
                          const float* __restrict__ w1, const float* __restrict__ b1,
                          const float* __restrict__ w2, const float* __restrict__ b2,
                          const float* __restrict__ wbs, const float* __restrict__ bbs,
                          float* __restrict__ out, int E)
{
    __shared__ __align__(16) short wslot[128 * 2 * 128];
    __shared__ __align__(16) float t_lds[128 * TPITCH];
    const int tid = threadIdx.x, lane = tid & 63, wid = tid >> 6;
    const int row0 = blockIdx.x * 128 + wid * 16;
    const int acol = lane & 15, kq = lane >> 4;

    const int arow = row0 + acol;
    const bool av = arow < E;
    const float* hr = h0 + (size_t)arow * 128;
    float va[4][8];
    #pragma unroll
    for (int ks = 0; ks < 4; ++ks) {
        #pragma unroll
        for (int jj = 0; jj < 8; ++jj) va[ks][jj] = 0.f;
        if (av) {
            const int k0 = ks * 32 + kq * 8;
            *(float4*)&va[ks][0] = *(const float4*)&hr[k0];
            *(float4*)&va[ks][4] = *(const float4*)&hr[k0 + 4];
        }
    }
    stage_w<128, 128>(w1, wslot, tid);
    __syncthreads();

    f32x4 acc[8];
    #pragma unroll
    for (int n = 0; n < 8; ++n)
        #pragma unroll
        for (int i = 0; i < 4; ++i) acc[n][i] = 0.f;
    #pragma unroll
    for (int ks = 0; ks < 4; ++ks) {
        bf16x8 ah, al; split8(va[ks], ah, al);
        mfma_step<128, 128, 8>(ah, al, wslot, ks * 32 + kq * 8, acol, acc);
    }
    #pragma unroll
    for (int n = 0; n < 8; ++n) {
        const int col = n * 16 + acol;
        const float bv = b1[col];
        #pragma unroll
        for (int r = 0; r < 4; ++r)
            t_lds[(wid * 16 + kq * 4 + r) * TPITCH + col] = silu_f(acc[n][r] + bv);
    }
    __syncthreads();
    stage_w<128, 128>(w2, wslot, tid);
    __syncthreads();

    // GEMM2 from t_lds; t2 = h0 + silu(acc2+b2) kept in registers
    f32x4 acc2[8];
    #pragma unroll
    for (int n = 0; n < 8; ++n)
        #pragma unroll
        for (int i = 0; i < 4; ++i) acc2[n][i] = 0.f;
    const float* trow = &t_lds[(wid * 16 + acol) * TPITCH];
    #pragma unroll
    for (int ks = 0; ks < 4; ++ks) {
        float v[8];
        const int k0 = ks * 32 + kq * 8;
        *(float4*)&v[0] = *(const float4*)&trow[k0];
        *(float4*)&v[4] = *(const float4*)&trow[k0 + 4];
        bf16x8 ah, al; split8(v, ah, al);
        mfma_step<128, 128, 8>(ah, al, wslot, k0, acol, acc2);
    }
    float t2[8][4];
    #pragma unroll
    for (int n = 0; n < 8; ++n) {
        const int col = n * 16 + acol;
        const float bv = b2[col];
        #pragma unroll
        for (int r = 0; r < 4; ++r) {
            const int ge = row0 + kq * 4 + r;
            const float hz = (ge < E) ? h0[(size_t)ge * 128 + col] : 0.f;
            t2[n][r] = hz + silu_f(acc2[n][r] + bv);
        }
    }
    __syncthreads();                    // all t1 reads complete
    #pragma unroll
    for (int n = 0; n < 8; ++n) {
        const int col = n * 16 + acol;
        #pragma unroll
        for (int r = 0; r < 4; ++r)
            t_lds[(wid * 16 + kq * 4 + r) * TPITCH + col] = t2[n][r];
    }
    stage_w<128, 128>(wbs, wslot, tid);
    __syncthreads();

    f32x4 acc3[8];
    #pragma unroll
    for (int n = 0; n < 8; ++n)
        #pragma unroll
        for (int i = 0; i < 4; ++i) acc3[n][i] = 0.f;
    #pragma unroll
    for (int ks = 0; ks < 4; ++ks) {
        float v[8];
        const int k0 = ks * 32 + kq * 8;
        *(float4*)&v[0] = *(const float4*)&trow[k0];
        *(float4*)&v[4] = *(const float4*)&trow[k0 + 4];
        bf16x8 ah, al; split8(v, ah, al);
        mfma_step<128, 128, 8>(ah, al, wslot, k0, acol, acc3);
    }
    #pragma unroll
    for (int n = 0; n < 8; ++n) {
        const int col = n * 16 + acol;
        const float bv = bbs[col];
        #pragma unroll
        for (int r = 0; r < 4; ++r) {
            const int ge = row0 + kq * 4 + r;
            if (ge < E)
                out[(size_t)ge * 128 + col] = silu_f(acc3[n][r] + bv) + x[(size_t)ge * 128 + col];
        }
    }
}

// ---------------- res block, in-place: h += silu(silu(h@w1+b1)@w2+b2) -------
__launch_bounds__(512, 1)
__global__ void res_kernel(float* __restrict__ h,
                           const float* __restrict__ w1, const float* __restrict__ b1,
                           const float* __restrict__ w2, const float* __restrict__ b2, int E)
{
    __shared__ __align__(16) short wslot[128 * 2 * 128];
    __shared__ __align__(16) float t_lds[128 * TPITCH];
    const int tid = threadIdx.x, lane = tid & 63, wid = tid >> 6;
    const int row0 = blockIdx.x * 128 + wid * 16;
    const int acol = lane & 15, kq = lane >> 4;

    const int arow = row0 + acol;
    const bool av = arow < E;
    const float* hr = h + (size_t)arow * 128;
    float va[4][8];
    #pragma unroll
    for (int ks = 0; ks < 4; ++ks) {
        #pragma unroll
        for (int jj = 0; jj < 8; ++jj) va[ks][jj] = 0.f;
        if (av) {
            const int k0 = ks * 32 + kq * 8;
            *(float4*)&va[ks][0] = *(const float4*)&hr[k0];
            *(float4*)&va[ks][4] = *(const float4*)&hr[k0 + 4];
        }
    }
    stage_w<128, 128>(w1, wslot, tid);
    __syncthreads();

    f32x4 acc[8];
    #pragma unroll
    for (int n = 0; n < 8; ++n)
        #pragma unroll
        for (int i = 0; i < 4; ++i) acc[n][i] = 0.f;
    #pragma unroll
    for (int ks = 0; ks < 4; ++ks) {
        bf16x8 ah, al; split8(va[ks], ah, al);
        mfma_step<128, 128, 8>(ah, al, wslot, ks * 32 + kq * 8, acol, acc);
    }
    #pragma unroll
    for (int n = 0; n < 8; ++n) {
        const int col = n * 16 + acol;
        const float bv = b1[col];
        #pragma unroll
        for (int r = 0; r < 4; ++r)
            t_lds[(wid * 16 + kq * 4 + r) * TPITCH + col] = silu_f(acc[n][r] + bv);
    }
    __syncthreads();
    stage_w<128, 128>(w2, wslot, tid);
    __syncthreads();

    f32x4 acc2[8];
    #pragma unroll
    for (int n = 0; n < 8; ++n)
        #pragma unroll
        for (int i = 0; i < 4; ++i) acc2[n][i] = 0.f;
    const float* trow = &t_lds[(wid * 16 + acol) * TPITCH];
    #pragma unroll
    for (int ks = 0; ks < 4; ++ks) {
        float v[8];
        const int k0 = ks * 32 + kq * 8;
        *(float4*)&v[0] = *(const float4*)&trow[k0];
        *(float4*)&v[4] = *(const float4*)&trow[k0 + 4];
        bf16x8 ah, al; split8(v, ah, al);
        mfma_step<128, 128, 8>(ah, al, wslot, k0, acol, acc2);
    }
    #pragma unroll
    for (int n = 0; n < 8; ++n) {
        const int col = n * 16 + acol;
        const float bv = b2[col];
        #pragma unroll
        for (int r = 0; r < 4; ++r) {
            const int ge = row0 + kq * 4 + r;
            if (ge < E) {
                const float hz = h[(size_t)ge * 128 + col];
                h[(size_t)ge * 128 + col] = hz + silu_f(acc2[n][r] + bv);
            }
        }
    }
}

// ---------------------------------------------------------------------------

extern "C" void kernel_launch(void* const* d_in, const int* in_sizes, int n_in,
                              void* d_out, int out_size, void* d_ws, size_t ws_size,
                              hipStream_t stream)
{
    const float* x      = (const float*)d_in[0];
    const float* rbf    = (const float*)d_in[1];
    const float* sbf    = (const float*)d_in[2];
    const int*   idx_kj = (const int*)d_in[3];
    const int*   idx_ji = (const int*)d_in[4];
    const float* w_rbf1 = (const float*)d_in[5];
    const float* w_rbf2 = (const float*)d_in[6];
    const float* w_sbf1 = (const float*)d_in[7];
    const float* w_sbf2 = (const float*)d_in[8];
    const float* w_kj   = (const float*)d_in[9];
    const float* b_kj   = (const float*)d_in[10];
    const float* w_ji   = (const float*)d_in[11];
    const float* b_ji   = (const float*)d_in[12];
    const float* w_down = (const float*)d_in[13];
    const float* w_up   = (const float*)d_in[14];
    const float* r1w1   = (const float*)d_in[15];
    const float* r1b1   = (const float*)d_in[16];
    const float* r1w2   = (const float*)d_in[17];
    const float* r1b2   = (const float*)d_in[18];
    const float* w_bs   = (const float*)d_in[19];
    const float* b_bs   = (const float*)d_in[20];
    const float* r2w1   = (const float*)d_in[21];
    const float* r2b1   = (const float*)d_in[22];
    const float* r2w2   = (const float*)d_in[23];
    const float* r2b2   = (const float*)d_in[24];
    const float* r3w1   = (const float*)d_in[25];
    const float* r3b1   = (const float*)d_in[26];
    const float* r3w2   = (const float*)d_in[27];
    const float* r3b2   = (const float*)d_in[28];

    const int E = in_sizes[0] / 128;
    const int T = in_sizes[2] / 42;

    float* OUT = (float*)d_out;
    float* W1  = (float*)d_ws;                                        // [E,128] h0
    float* W3  = (float*)((char*)d_ws + (size_t)E * 128 * 4);         // [E,64]
    float* W4  = (float*)((char*)d_ws + (size_t)E * 128 * 4
                                      + (size_t)E * 64 * 4);          // [E,64]

    // Overlays inside the W1 region (all dead before K4 writes h0):
    int*   cnt      = (int*)W1;                              // [E]  (cursor after scan)
    int*   offsets  = cnt + (E + 64);                        // [E+1]
    int*   partial  = offsets + (E + 64);                    // [<=1024]
    int*   blockoff = partial + 1024;                        // [<=1024]
    float* E1p      = (float*)((char*)d_ws + (4u << 20));    // [T,8]  96MB
    int*   kjp      = (int*)((char*)d_ws + (102u << 20));    // [T]    12MB
    float* re1      = (float*)((char*)d_ws + (116u << 20));  // [E,8]  9.6MB

    const dim3 b256(256), b512(512);
    const int gB  = (E + 127) / 128;     // fused GEMM tiles
    const int gT  = (T + 255) / 256;
    const int NB  = (E + 1023) / 1024;
    const int gE4 = (E + 3) / 4;
    const int gR  = (E * 8 + 255) / 256;

    // prologue + CSR
    rbf1_kernel<<<gR, b256, 0, stream>>>(rbf, w_rbf1, re1, E);
    hipMemsetAsync(cnt, 0, (size_t)E * 4, stream);
    count_kernel<<<gT, b256, 0, stream>>>(idx_ji, cnt, T);
    scan_partial_kernel<<<NB, b256, 0, stream>>>(cnt, partial, E);
    scan_block_kernel<<<1, b256, 0, stream>>>(partial, blockoff, NB, offsets, E);
    scan_final_kernel<<<NB, b256, 0, stream>>>(cnt, blockoff, offsets, cnt, E);
    e1fill_kernel<<<gT, b256, 0, stream>>>(sbf, w_sbf1, idx_ji, idx_kj, cnt, E1p, kjp, T);

    // K1: x -> W3 (fused 2 GEMMs + rbf epilogue)
    k1_kernel<<<gB, b512, 0, stream>>>(x, w_kj, b_kj, re1, w_rbf2, w_down, W3, E);

    // gather: -> W4
    gather_kernel<<<gE4, b256, 0, stream>>>(E1p, kjp, w_sbf2, offsets, W3, W4, E);

    // K4: x, W4 -> h0 (W1)
    k4_kernel<<<gB, b512, 0, stream>>>(x, w_ji, b_ji, W4, w_up, W1, E);

    // K5: h0, x -> OUT (res1 + w_bs + skip, 3 GEMMs fused)
    k5_kernel<<<gB, b512, 0, stream>>>(W1, x, r1w1, r1b1, r1w2, r1b2, w_bs, b_bs, OUT, E);

    // K6, K7: in-place residual blocks on OUT
    res_kernel<<<gB, b512, 0, stream>>>(OUT, r2w1, r2b1, r2w2, r2b2, E);
    res_kernel<<<gB, b512, 0, stream>>>(OUT, r3w1, r3b1, r3w2, r3b2, E);
}

// Round 7
// 1285.157 us; speedup vs baseline: 1.2738x; 1.2738x over previous
//
#include <hip/hip_runtime.h>

// ---------------------------------------------------------------------------
// DimeNet++ interaction block, round 6:
//   - weights pre-converted ONCE to bf16 hi/lo LDS-image (swizzled) in d_ws
//   - GEMM kernels: 256 thr / 64 rows, 32-k slab pipeline, 2 named LDS slots,
//     async global_load_lds staging (issue -> MFMA -> barrier), 2 blocks/CU
//   - h0 lives in d_out (in-place row-local updates) freeing d_ws for weights
// ---------------------------------------------------------------------------

typedef __attribute__((ext_vector_type(8))) short bf16x8;
typedef __attribute__((ext_vector_type(4))) float f32x4;

__device__ __forceinline__ float silu_f(float v) { return v / (1.0f + __expf(-v)); }
__device__ __forceinline__ short f2bf(float f) {
    unsigned u = __float_as_uint(f);
    unsigned r = u + 0x7fffu + ((u >> 16) & 1u);
    return (short)(r >> 16);
}
__device__ __forceinline__ float bf2f(short s) {
    return __uint_as_float(((unsigned)(unsigned short)s) << 16);
}
__device__ __forceinline__ void split44(f32x4 a, f32x4 b, bf16x8& hi, bf16x8& lo) {
    #pragma unroll
    for (int j = 0; j < 4; ++j) { short h = f2bf(a[j]); hi[j] = h; lo[j] = f2bf(a[j] - bf2f(h)); }
    #pragma unroll
    for (int j = 0; j < 4; ++j) { short h = f2bf(b[j]); hi[4 + j] = h; lo[4 + j] = f2bf(b[j] - bf2f(h)); }
}

__device__ __forceinline__ void gll16(const void* g, void* l) {
    __builtin_amdgcn_global_load_lds((const __attribute__((address_space(1))) void*)g,
                                     (__attribute__((address_space(3))) void*)l, 16, 0, 0);
}
// stage a 16 KB slab (N=128) : 4 wave-iters x 1KB per wave
__device__ __forceinline__ void stage16(const char* g, short* l, int lane, int wid) {
    #pragma unroll
    for (int i = 0; i < 4; ++i) {
        const int off = ((i * 4 + wid) << 10);
        gll16(g + off + lane * 16, (char*)l + off);
    }
}
// stage an 8 KB slab (N=64)
__device__ __forceinline__ void stage8(const char* g, short* l, int lane, int wid) {
    #pragma unroll
    for (int i = 0; i < 2; ++i) {
        const int off = ((i * 4 + wid) << 10);
        gll16(g + off + lane * 16, (char*)l + off);
    }
}

// slab layout (per 32-k slab, col c, plane p(0=hi,1=lo), chunk ch(0..3) of 8 bf16):
//   byte = c*128 + (p ^ ((c>>2)&1))*64 + ((ch ^ (c&3))*16)
// conflict-free for wave b128 reads (verified bank math), linear for gll writes.
template<int NF>
__device__ __forceinline__ void mfma_ks(bf16x8 ah, bf16x8 al, const short* slot,
                                        int acol, int kq, f32x4* acc) {
    #pragma unroll
    for (int n = 0; n < NF; ++n) {
        const int c = n * 16 + acol;
        const int x = (c >> 2) & 1;
        const int sw = (kq ^ (c & 3)) << 3;      // shorts
        const bf16x8 bh = *(const bf16x8*)&slot[c * 64 + x * 32 + sw];
        const bf16x8 bl = *(const bf16x8*)&slot[c * 64 + (x ^ 1) * 32 + sw];
        acc[n] = __builtin_amdgcn_mfma_f32_16x16x32_bf16(ah, bh, acc[n], 0, 0, 0);
        acc[n] = __builtin_amdgcn_mfma_f32_16x16x32_bf16(al, bh, acc[n], 0, 0, 0);
        acc[n] = __builtin_amdgcn_mfma_f32_16x16x32_bf16(ah, bl, acc[n], 0, 0, 0);
    }
}
template<int NF>
__device__ __forceinline__ void gphase(f32x4 a0, f32x4 a1, const short* slot,
                                       int acol, int kq, f32x4* acc) {
    bf16x8 ah, al; split44(a0, a1, ah, al);
    mfma_ks<NF>(ah, al, slot, acol, kq, acc);
}
template<int NF>
__device__ __forceinline__ void tphase(const float* tl, int rowbase, int q,
                                       int kq, int acol, const short* slot, f32x4* acc) {
    const f32x4 ta = *(const f32x4*)&tl[rowbase + q * 32 + kq * 8];
    const f32x4 tb = *(const f32x4*)&tl[rowbase + q * 32 + kq * 8 + 4];
    bf16x8 ah, al; split44(ta, tb, ah, al);
    mfma_ks<NF>(ah, al, slot, acol, kq, acc);
}

#define TPITCH 132

// ---------------- weight pre-conversion -------------------------------------
struct WDesc { const float* src; char* dst; int K; int N; };
struct WPrepArgs { WDesc w[11]; };

__global__ void wprep_kernel(WPrepArgs args) {
    const WDesc d = args.w[blockIdx.y];
    const int h = blockIdx.x;
    if (h * 32 >= d.K) return;
    char* slab = d.dst + (size_t)h * d.N * 128;
    for (int idx = threadIdx.x; idx < d.N * 4; idx += 256) {
        const int c = idx >> 2, ch = idx & 3;
        bf16x8 hi, lo;
        #pragma unroll
        for (int j = 0; j < 8; ++j) {
            const float f = d.src[(size_t)(h * 32 + ch * 8 + j) * d.N + c];
            const short hb = f2bf(f);
            hi[j] = hb;
            lo[j] = f2bf(f - bf2f(hb));
        }
        const int x = (c >> 2) & 1;
        const int sw = (ch ^ (c & 3)) * 16;
        *(bf16x8*)(slab + c * 128 + x * 64 + sw)       = hi;
        *(bf16x8*)(slab + c * 128 + (x ^ 1) * 64 + sw) = lo;
    }
}

// ---------------- small prologue kernels ------------------------------------

__global__ void rbf1_kernel(const float* __restrict__ rbf, const float* __restrict__ w_rbf1,
                            float* __restrict__ re1, int E) {
    const int i = blockIdx.x * 256 + threadIdx.x;
    const int e = i >> 3, p = i & 7;
    if (e < E) {
        float s = 0.f;
        #pragma unroll
        for (int q = 0; q < 6; ++q) s = fmaf(rbf[e * 6 + q], w_rbf1[q * 8 + p], s);
        re1[i] = s;
    }
}

__global__ void count_kernel(const int* __restrict__ idx_ji, int* __restrict__ cnt, int T) {
    const int t = blockIdx.x * 256 + threadIdx.x;
    if (t < T) atomicAdd(&cnt[idx_ji[t]], 1);
}

__global__ void scan_partial_kernel(const int* __restrict__ cnt, int* __restrict__ partial, int E) {
    __shared__ int red[256];
    const int tid = threadIdx.x;
    const int base = blockIdx.x * 1024 + tid * 4;
    int s = 0;
    #pragma unroll
    for (int i = 0; i < 4; ++i) { const int g = base + i; if (g < E) s += cnt[g]; }
    red[tid] = s;
    __syncthreads();
    for (int off = 128; off > 0; off >>= 1) {
        if (tid < off) red[tid] += red[tid + off];
        __syncthreads();
    }
    if (tid == 0) partial[blockIdx.x] = red[0];
}

__global__ void scan_block_kernel(const int* __restrict__ partial, int* __restrict__ blockoff,
                                  int NB, int* offsets, int E) {
    __shared__ int red[256];
    const int tid = threadIdx.x;
    int v[4]; int s = 0;
    #pragma unroll
    for (int i = 0; i < 4; ++i) { const int g = tid * 4 + i; v[i] = (g < NB) ? partial[g] : 0; s += v[i]; }
    red[tid] = s;
    __syncthreads();
    for (int off = 1; off < 256; off <<= 1) {
        const int add = (tid >= off) ? red[tid - off] : 0;
        __syncthreads();
        red[tid] += add;
        __syncthreads();
    }
    int excl = (tid == 0) ? 0 : red[tid - 1];
    #pragma unroll
    for (int i = 0; i < 4; ++i) { const int g = tid * 4 + i; if (g < NB) blockoff[g] = excl; excl += v[i]; }
    if (tid == 255) offsets[E] = red[255];
}

__global__ void scan_final_kernel(const int* cnt, const int* __restrict__ blockoff,
                                  int* offsets, int* cursor, int E) {
    __shared__ int red[256];
    const int tid = threadIdx.x;
    const int base = blockIdx.x * 1024 + tid * 4;
    int v[4]; int s = 0;
    #pragma unroll
    for (int i = 0; i < 4; ++i) { const int g = base + i; v[i] = (g < E) ? cnt[g] : 0; s += v[i]; }
    red[tid] = s;
    __syncthreads();
    for (int off = 1; off < 256; off <<= 1) {
        const int add = (tid >= off) ? red[tid - off] : 0;
        __syncthreads();
        red[tid] += add;
        __syncthreads();
    }
    int run = blockoff[blockIdx.x] + ((tid == 0) ? 0 : red[tid - 1]);
    #pragma unroll
    for (int i = 0; i < 4; ++i) {
        const int g = base + i;
        if (g < E) { offsets[g] = run; cursor[g] = run; }
        run += v[i];
    }
}

__launch_bounds__(256, 4)
__global__ void e1fill_kernel(const float* __restrict__ sbf, const float* __restrict__ w_sbf1,
                              const int* __restrict__ idx_ji, const int* __restrict__ idx_kj,
                              int* __restrict__ cursor,
                              float* __restrict__ E1p, int* __restrict__ kjp, int T) {
    const int t = blockIdx.x * 256 + threadIdx.x;
    if (t >= T) return;
    const float* srow = sbf + (size_t)t * 42;
    float e1[8] = {0.f, 0.f, 0.f, 0.f, 0.f, 0.f, 0.f, 0.f};
    #pragma unroll
    for (int q = 0; q < 42; q += 2) {
        const float2 sv = *(const float2*)&srow[q];
        #pragma unroll
        for (int p = 0; p < 8; ++p) {
            e1[p] = fmaf(sv.x, w_sbf1[q * 8 + p], e1[p]);
            e1[p] = fmaf(sv.y, w_sbf1[(q + 1) * 8 + p], e1[p]);
        }
    }
    const int pos = atomicAdd(&cursor[idx_ji[t]], 1);
    *(float4*)&E1p[(size_t)pos * 8]     = *(float4*)&e1[0];
    *(float4*)&E1p[(size_t)pos * 8 + 4] = *(float4*)&e1[4];
    kjp[pos] = idx_kj[t];
}

__launch_bounds__(256, 4)
__global__ void gather_kernel(const float* __restrict__ E1p, const int* __restrict__ kjp,
                              const float* __restrict__ w_sbf2, const int* __restrict__ offsets,
                              const float* __restrict__ xkjd, float* __restrict__ agg, int E)
{
    const int tid  = threadIdx.x;
    const int lane = tid & 63;
    const int e    = blockIdx.x * 4 + (tid >> 6);

    float w2[8];
    #pragma unroll
    for (int p = 0; p < 8; ++p) w2[p] = w_sbf2[p * 64 + lane];

    if (e >= E) return;
    const int j0 = __builtin_amdgcn_readfirstlane(offsets[e]);
    const int j1 = __builtin_amdgcn_readfirstlane(offsets[e + 1]);

    float acc = 0.f;
    if (j0 < j1) {
        int kj = __builtin_amdgcn_readfirstlane(kjp[j0]);
        float4 ea = *(const float4*)&E1p[(size_t)j0 * 8];
        float4 eb = *(const float4*)&E1p[(size_t)j0 * 8 + 4];
        for (int j = j0; j < j1; ++j) {
            const float xv = xkjd[(size_t)kj * 64 + lane];
            int kn = 0; float4 ean = {}, ebn = {};
            if (j + 1 < j1) {
                kn  = __builtin_amdgcn_readfirstlane(kjp[j + 1]);
                ean = *(const float4*)&E1p[(size_t)(j + 1) * 8];
                ebn = *(const float4*)&E1p[(size_t)(j + 1) * 8 + 4];
            }
            float sv = ea.x * w2[0];
            sv = fmaf(ea.y, w2[1], sv);
            sv = fmaf(ea.z, w2[2], sv);
            sv = fmaf(ea.w, w2[3], sv);
            sv = fmaf(eb.x, w2[4], sv);
            sv = fmaf(eb.y, w2[5], sv);
            sv = fmaf(eb.z, w2[6], sv);
            sv = fmaf(eb.w, w2[7], sv);
            acc = fmaf(xv, sv, acc);
            kj = kn; ea = ean; eb = ebn;
        }
    }
    agg[(size_t)e * 64 + lane] = acc;
}

// ---------------- K1: W3 = silu((silu(x@w_kj+b)*rbf_e)@w_down) --------------
__launch_bounds__(256, 2)
__global__ void k1_kernel(const float* __restrict__ x, const char* __restrict__ wkj_i,
                          const float* __restrict__ b_kj, const float* __restrict__ re1,
                          const float* __restrict__ w_rbf2, const char* __restrict__ wdn_i,
                          float* __restrict__ W3, int E)
{
    __shared__ short slotA[8192], slotB[8192];
    __shared__ float t_lds[64 * TPITCH];
    __shared__ float w2_lds[8 * 128];
    const int tid = threadIdx.x, lane = tid & 63, wid = tid >> 6;
    const int acol = lane & 15, kq = lane >> 4;
    const int rowW = blockIdx.x * 64 + wid * 16;
    const int arow = rowW + acol;
    const bool av = arow < E;

    stage16(wkj_i, slotA, lane, wid);
    const float* xr = x + (size_t)arow * 128;
    f32x4 a[4][2];
    #pragma unroll
    for (int ks = 0; ks < 4; ++ks) {
        a[ks][0] = f32x4{0.f, 0.f, 0.f, 0.f}; a[ks][1] = f32x4{0.f, 0.f, 0.f, 0.f};
        if (av) { a[ks][0] = *(const f32x4*)&xr[ks * 32 + kq * 8];
                  a[ks][1] = *(const f32x4*)&xr[ks * 32 + kq * 8 + 4]; }
    }
    float bv[8];
    #pragma unroll
    for (int n = 0; n < 8; ++n) bv[n] = b_kj[n * 16 + acol];
    f32x4 e1a[4], e1b[4];
    #pragma unroll
    for (int r = 0; r < 4; ++r) {
        const int ge = rowW + kq * 4 + r;
        e1a[r] = f32x4{0.f, 0.f, 0.f, 0.f}; e1b[r] = f32x4{0.f, 0.f, 0.f, 0.f};
        if (ge < E) { e1a[r] = *(const f32x4*)&re1[(size_t)ge * 8];
                      e1b[r] = *(const f32x4*)&re1[(size_t)ge * 8 + 4]; }
    }
    for (int i = tid; i < 1024; i += 256) w2_lds[i] = w_rbf2[i];
    __syncthreads();

    f32x4 acc[8];
    #pragma unroll
    for (int n = 0; n < 8; ++n) acc[n] = f32x4{0.f, 0.f, 0.f, 0.f};

    stage16(wkj_i + 16384, slotB, lane, wid);
    gphase<8>(a[0][0], a[0][1], slotA, acol, kq, acc); __syncthreads();
    stage16(wkj_i + 32768, slotA, lane, wid);
    gphase<8>(a[1][0], a[1][1], slotB, acol, kq, acc); __syncthreads();
    stage16(wkj_i + 49152, slotB, lane, wid);
    gphase<8>(a[2][0], a[2][1], slotA, acol, kq, acc); __syncthreads();
    stage8(wdn_i, slotA, lane, wid);
    gphase<8>(a[3][0], a[3][1], slotB, acol, kq, acc); __syncthreads();

    // t = silu(acc + b) * (re1 . w_rbf2[:,c])
    #pragma unroll
    for (int n = 0; n < 8; ++n) {
        const int c = n * 16 + acol;
        float w2c[8];
        #pragma unroll
        for (int p = 0; p < 8; ++p) w2c[p] = w2_lds[p * 128 + c];
        #pragma unroll
        for (int r = 0; r < 4; ++r) {
            float s = e1a[r][0] * w2c[0];
            s = fmaf(e1a[r][1], w2c[1], s);
            s = fmaf(e1a[r][2], w2c[2], s);
            s = fmaf(e1a[r][3], w2c[3], s);
            s = fmaf(e1b[r][0], w2c[4], s);
            s = fmaf(e1b[r][1], w2c[5], s);
            s = fmaf(e1b[r][2], w2c[6], s);
            s = fmaf(e1b[r][3], w2c[7], s);
            t_lds[(wid * 16 + kq * 4 + r) * TPITCH + c] = silu_f(acc[n][r] + bv[n]) * s;
        }
    }
    __syncthreads();

    f32x4 acc2[4];
    #pragma unroll
    for (int n = 0; n < 4; ++n) acc2[n] = f32x4{0.f, 0.f, 0.f, 0.f};
    const int rb = (wid * 16 + acol) * TPITCH;

    stage8(wdn_i + 8192, slotB, lane, wid);
    tphase<4>(t_lds, rb, 0, kq, acol, slotA, acc2); __syncthreads();
    stage8(wdn_i + 16384, slotA, lane, wid);
    tphase<4>(t_lds, rb, 1, kq, acol, slotB, acc2); __syncthreads();
    stage8(wdn_i + 24576, slotB, lane, wid);
    tphase<4>(t_lds, rb, 2, kq, acol, slotA, acc2); __syncthreads();
    tphase<4>(t_lds, rb, 3, kq, acol, slotB, acc2);

    #pragma unroll
    for (int n = 0; n < 4; ++n) {
        const int c = n * 16 + acol;
        #pragma unroll
        for (int r = 0; r < 4; ++r) {
            const int ge = rowW + kq * 4 + r;
            if (ge < E) W3[(size_t)ge * 64 + c] = silu_f(acc2[n][r]);
        }
    }
}

// ---------------- K4: h0 = silu(x@w_ji+b_ji) + silu(W4@w_up) ----------------
__launch_bounds__(256, 2)
__global__ void k4_kernel(const float* __restrict__ x, const char* __restrict__ wji_i,
                          const float* __restrict__ b_ji, const float* __restrict__ W4,
                          const char* __restrict__ wup_i, float* __restrict__ h0, int E)
{
    __shared__ short slotA[8192], slotB[8192];
    const int tid = threadIdx.x, lane = tid & 63, wid = tid >> 6;
    const int acol = lane & 15, kq = lane >> 4;
    const int rowW = blockIdx.x * 64 + wid * 16;
    const int arow = rowW + acol;
    const bool av = arow < E;

    stage16(wji_i, slotA, lane, wid);
    const float* xr = x + (size_t)arow * 128;
    const float* wr = W4 + (size_t)arow * 64;
    f32x4 a[4][2], u[2][2];
    #pragma unroll
    for (int ks = 0; ks < 4; ++ks) {
        a[ks][0] = f32x4{0.f, 0.f, 0.f, 0.f}; a[ks][1] = f32x4{0.f, 0.f, 0.f, 0.f};
        if (av) { a[ks][0] = *(const f32x4*)&xr[ks * 32 + kq * 8];
                  a[ks][1] = *(const f32x4*)&xr[ks * 32 + kq * 8 + 4]; }
    }
    #pragma unroll
    for (int ks = 0; ks < 2; ++ks) {
        u[ks][0] = f32x4{0.f, 0.f, 0.f, 0.f}; u[ks][1] = f32x4{0.f, 0.f, 0.f, 0.f};
        if (av) { u[ks][0] = *(const f32x4*)&wr[ks * 32 + kq * 8];
                  u[ks][1] = *(const f32x4*)&wr[ks * 32 + kq * 8 + 4]; }
    }
    float bv[8];
    #pragma unroll
    for (int n = 0; n < 8; ++n) bv[n] = b_ji[n * 16 + acol];
    __syncthreads();

    f32x4 acc1[8], acc2[8];
    #pragma unroll
    for (int n = 0; n < 8; ++n) { acc1[n] = f32x4{0.f, 0.f, 0.f, 0.f}; acc2[n] = f32x4{0.f, 0.f, 0.f, 0.f}; }

    stage16(wji_i + 16384, slotB, lane, wid);
    gphase<8>(a[0][0], a[0][1], slotA, acol, kq, acc1); __syncthreads();
    stage16(wji_i + 32768, slotA, lane, wid);
    gphase<8>(a[1][0], a[1][1], slotB, acol, kq, acc1); __syncthreads();
    stage16(wji_i + 49152, slotB, lane, wid);
    gphase<8>(a[2][0], a[2][1], slotA, acol, kq, acc1); __syncthreads();
    stage16(wup_i, slotA, lane, wid);
    gphase<8>(a[3][0], a[3][1], slotB, acol, kq, acc1); __syncthreads();
    stage16(wup_i + 16384, slotB, lane, wid);
    gphase<8>(u[0][0], u[0][1], slotA, acol, kq, acc2); __syncthreads();
    gphase<8>(u[1][0], u[1][1], slotB, acol, kq, acc2);

    #pragma unroll
    for (int n = 0; n < 8; ++n) {
        const int c = n * 16 + acol;
        #pragma unroll
        for (int r = 0; r < 4; ++r) {
            const int ge = rowW + kq * 4 + r;
            if (ge < E)
                h0[(size_t)ge * 128 + c] = silu_f(acc1[n][r] + bv[n]) + silu_f(acc2[n][r]);
        }
    }
}

// ---------------- K5: OUT = silu(res1(h0)@w_bs+b_bs) + x  (in-place on h0) --
__launch_bounds__(256, 2)
__global__ void k5_kernel(float* __restrict__ h, const float* __restrict__ x,
                          const char* __restrict__ w1i, const float* __restrict__ b1,
                          const char* __restrict__ w2i, const float* __restrict__ b2,
                          const char* __restrict__ wbsi, const float* __restrict__ bbs,
                          int E)
{
    __shared__ short slotA[8192], slotB[8192];
    __shared__ float t_lds[64 * TPITCH];
    const int tid = threadIdx.x, lane = tid & 63, wid = tid >> 6;
    const int acol = lane & 15, kq = lane >> 4;
    const int rowW = blockIdx.x * 64 + wid * 16;
    const int arow = rowW + acol;
    const bool av = arow < E;

    stage16(w1i, slotA, lane, wid);
    const float* hr = h + (size_t)arow * 128;
    f32x4 a[4][2];
    #pragma unroll
    for (int ks = 0; ks < 4; ++ks) {
        a[ks][0] = f32x4{0.f, 0.f, 0.f, 0.f}; a[ks][1] = f32x4{0.f, 0.f, 0.f, 0.f};
        if (av) { a[ks][0] = *(const f32x4*)&hr[ks * 32 + kq * 8];
                  a[ks][1] = *(const f32x4*)&hr[ks * 32 + kq * 8 + 4]; }
    }
    float b1v[8], b2v[8], bbsv[8], hres[8][4];
    #pragma unroll
    for (int n = 0; n < 8; ++n) {
        b1v[n] = b1[n * 16 + acol]; b2v[n] = b2[n * 16 + acol]; bbsv[n] = bbs[n * 16 + acol];
    }
    #pragma unroll
    for (int r = 0; r < 4; ++r) {
        const int ge = rowW + kq * 4 + r;
        #pragma unroll
        for (int n = 0; n < 8; ++n)
            hres[n][r] = (ge < E) ? h[(size_t)ge * 128 + n * 16 + acol] : 0.f;
    }
    __syncthreads();

    f32x4 acc[8];
    #pragma unroll
    for (int n = 0; n < 8; ++n) acc[n] = f32x4{0.f, 0.f, 0.f, 0.f};

    stage16(w1i + 16384, slotB, lane, wid);
    gphase<8>(a[0][0], a[0][1], slotA, acol, kq, acc); __syncthreads();
    stage16(w1i + 32768, slotA, lane, wid);
    gphase<8>(a[1][0], a[1][1], slotB, acol, kq, acc); __syncthreads();
    stage16(w1i + 49152, slotB, lane, wid);
    gphase<8>(a[2][0], a[2][1], slotA, acol, kq, acc); __syncthreads();
    stage16(w2i, slotA, lane, wid);
    gphase<8>(a[3][0], a[3][1], slotB, acol, kq, acc); __syncthreads();

    #pragma unroll
    for (int n = 0; n < 8; ++n) {
        const int c = n * 16 + acol;
        #pragma unroll
        for (int r = 0; r < 4; ++r)
            t_lds[(wid * 16 + kq * 4 + r) * TPITCH + c] = silu_f(acc[n][r] + b1v[n]);
    }
    __syncthreads();

    f32x4 acc2[8];
    #pragma unroll
    for (int n = 0; n < 8; ++n) acc2[n] = f32x4{0.f, 0.f, 0.f, 0.f};
    const int rb = (wid * 16 + acol) * TPITCH;

    stage16(w2i + 16384, slotB, lane, wid);
    tphase<8>(t_lds, rb, 0, kq, acol, slotA, acc2); __syncthreads();
    stage16(w2i + 32768, slotA, lane, wid);
    tphase<8>(t_lds, rb, 1, kq, acol, slotB, acc2); __syncthreads();
    stage16(w2i + 49152, slotB, lane, wid);
    tphase<8>(t_lds, rb, 2, kq, acol, slotA, acc2); __syncthreads();
    stage16(wbsi, slotA, lane, wid);
    tphase<8>(t_lds, rb, 3, kq, acol, slotB, acc2); __syncthreads();

    // t2 = h + silu(acc2 + b2)
    #pragma unroll
    for (int n = 0; n < 8; ++n) {
        const int c = n * 16 + acol;
        #pragma unroll
        for (int r = 0; r < 4; ++r)
            t_lds[(wid * 16 + kq * 4 + r) * TPITCH + c] = hres[n][r] + silu_f(acc2[n][r] + b2v[n]);
    }
    __syncthreads();

    // xres loads (consumed in final epilogue)
    float xres[8][4];
    #pragma unroll
    for (int r = 0; r < 4; ++r) {
        const int ge = rowW + kq * 4 + r;
        #pragma unroll
        for (int n = 0; n < 8; ++n)
            xres[n][r] = (ge < E) ? x[(size_t)ge * 128 + n * 16 + acol] : 0.f;
    }

    f32x4 acc3[8];
    #pragma unroll
    for (int n = 0; n < 8; ++n) acc3[n] = f32x4{0.f, 0.f, 0.f, 0.f};

    stage16(wbsi + 16384, slotB, lane, wid);
    tphase<8>(t_lds, rb, 0, kq, acol, slotA, acc3); __syncthreads();
    stage16(wbsi + 32768, slotA, lane, wid);
    tphase<8>(t_lds, rb, 1, kq, acol, slotB, acc3); __syncthreads();
    stage16(wbsi + 49152, slotB, lane, wid);
    tphase<8>(t_lds, rb, 2, kq, acol, slotA, acc3); __syncthreads();
    tphase<8>(t_lds, rb, 3, kq, acol, slotB, acc3);

    #pragma unroll
    for (int n = 0; n < 8; ++n) {
        const int c = n * 16 + acol;
        #pragma unroll
        for (int r = 0; r < 4; ++r) {
            const int ge = rowW + kq * 4 + r;
            if (ge < E)
                h[(size_t)ge * 128 + c] = silu_f(acc3[n][r] + bbsv[n]) + xres[n][r];
        }
    }
}

// ---------------- res block, in-place: h += silu(silu(h@w1+b1)@w2+b2) -------
__launch_bounds__(256, 2)
__global__ void res_kernel(float* __restrict__ h,
                           const char* __restrict__ w1i, const float* __restrict__ b1,
                           const char* __restrict__ w2i, const float* __restrict__ b2, int E)
{
    __shared__ short slotA[8192], slotB[8192];
    __shared__ float t_lds[64 * TPITCH];
    const int tid = threadIdx.x, lane = tid & 63, wid = tid >> 6;
    const int acol = lane & 15, kq = lane >> 4;
    const int rowW = blockIdx.x * 64 + wid * 16;
    const int arow = rowW + acol;
    const bool av = arow < E;

    stage16(w1i, slotA, lane, wid);
    const float* hr = h + (size_t)arow * 128;
    f32x4 a[4][2];
    #pragma unroll
    for (int ks = 0; ks < 4; ++ks) {
        a[ks][0] = f32x4{0.f, 0.f, 0.f, 0.f}; a[ks][1] = f32x4{0.f, 0.f, 0.f, 0.f};
        if (av) { a[ks][0] = *(const f32x4*)&hr[ks * 32 + kq * 8];
                  a[ks][1] = *(const f32x4*)&hr[ks * 32 + kq * 8 + 4]; }
    }
    float b1v[8], b2v[8], hres[8][4];
    #pragma unroll
    for (int n = 0; n < 8; ++n) { b1v[n] = b1[n * 16 + acol]; b2v[n] = b2[n * 16 + acol]; }
    #pragma unroll
    for (int r = 0; r < 4; ++r) {
        const int ge = rowW + kq * 4 + r;
        #pragma unroll
        for (int n = 0; n < 8; ++n)
            hres[n][r] = (ge < E) ? h[(size_t)ge * 128 + n * 16 + acol] : 0.f;
    }
    __syncthreads();

    f32x4 acc[8];
    #pragma unroll
    for (int n = 0; n < 8; ++n) acc[n] = f32x4{0.f, 0.f, 0.f, 0.f};

    stage16(w1i + 16384, slotB, lane, wid);
    gphase<8>(a[0][0], a[0][1], slotA, acol, kq, acc); __syncthreads();
    stage16(w1i + 32768, slotA, lane, wid);
    gphase<8>(a[1][0], a[1][1], slotB, acol, kq, acc); __syncthreads();
    stage16(w1i + 49152, slotB, lane, wid);
    gphase<8>(a[2][0], a[2][1], slotA, acol, kq, acc); __syncthreads();
    stage16(w2i, slotA, lane, wid);
    gphase<8>(a[3][0], a[3][1], slotB, acol, kq, acc); __syncthreads();

    #pragma unroll
    for (int n = 0; n < 8; ++n) {
        const int c = n * 16 + acol;
        #pragma unroll
        for (int r = 0; r < 4; ++r)
            t_lds[(wid * 16 + kq * 4 + r) * TPITCH + c] = silu_f(acc[n][r] + b1v[n]);
    }
    __syncthreads();

    f32x4 acc2[8];
    #pragma unroll
    for (int n = 0; n < 8; ++n) acc2[n] = f32x4{0.f, 0.f, 0.f, 0.f};
    const int rb = (wid * 16 + acol) * TPITCH;

    stage16(w2i + 16384, slotB, lane, wid);
    tphase<8>(t_lds, rb, 0, kq, acol, slotA, acc2); __syncthreads();
    stage16(w2i + 32768, slotA, lane, wid);
    tphase<8>(t_lds, rb, 1, kq, acol, slotB, acc2); __syncthreads();
    stage16(w2i + 49152, slotB, lane, wid);
    tphase<8>(t_lds, rb, 2, kq, acol, slotA, acc2); __syncthreads();
    tphase<8>(t_lds, rb, 3, kq, acol, slotB, acc2);

    #pragma unroll
    for (int n = 0; n < 8; ++n) {
        const int c = n * 16 + acol;
        #pragma unroll
        for (int r = 0; r < 4; ++r) {
            const int ge = rowW + kq * 4 + r;
            if (ge < E)
                h[(size_t)ge * 128 + c] = hres[n][r] + silu_f(acc2[n][r] + b2v[n]);
        }
    }
}

// ---------------------------------------------------------------------------

extern "C" void kernel_launch(void* const* d_in, const int* in_sizes, int n_in,
                              void* d_out, int out_size, void* d_ws, size_t ws_size,
                              hipStream_t stream)
{
    const float* x      = (const float*)d_in[0];
    const float* rbf    = (const float*)d_in[1];
    const float* sbf    = (const float*)d_in[2];
    const int*   idx_kj = (const int*)d_in[3];
    const int*   idx_ji = (const int*)d_in[4];
    const float* w_rbf1 = (const float*)d_in[5];
    const float* w_rbf2 = (const float*)d_in[6];
    const float* w_sbf1 = (const float*)d_in[7];
    const float* w_sbf2 = (const float*)d_in[8];
    const float* w_kj   = (const float*)d_in[9];
    const float* b_kj   = (const float*)d_in[10];
    const float* w_ji   = (const float*)d_in[11];
    const float* b_ji   = (const float*)d_in[12];
    const float* w_down = (const float*)d_in[13];
    const float* w_up   = (const float*)d_in[14];
    const float* r1w1   = (const float*)d_in[15];
    const float* r1b1   = (const float*)d_in[16];
    const float* r1w2   = (const float*)d_in[17];
    const float* r1b2   = (const float*)d_in[18];
    const float* w_bs   = (const float*)d_in[19];
    const float* b_bs   = (const float*)d_in[20];
    const float* r2w1   = (const float*)d_in[21];
    const float* r2b1   = (const float*)d_in[22];
    const float* r2w2   = (const float*)d_in[23];
    const float* r2b2   = (const float*)d_in[24];
    const float* r3w1   = (const float*)d_in[25];
    const float* r3b1   = (const float*)d_in[26];
    const float* r3w2   = (const float*)d_in[27];
    const float* r3b2   = (const float*)d_in[28];

    const int E = in_sizes[0] / 128;
    const int T = in_sizes[2] / 42;

    float* OUT = (float*)d_out;                                       // h0 / final
    float* W3  = (float*)((char*)d_ws + (size_t)E * 128 * 4);         // [E,64]
    float* W4  = (float*)((char*)d_ws + (size_t)E * 128 * 4
                                      + (size_t)E * 64 * 4);          // [E,64]

    // d_ws low region (h0 moved to d_out, so this whole region is scratch):
    int*   cnt      = (int*)d_ws;                            // [E]
    int*   offsets  = cnt + (E + 64);                        // [E+1]
    int*   partial  = offsets + (E + 64);                    // [<=1024]
    int*   blockoff = partial + 1024;                        // [<=1024]
    float* E1p      = (float*)((char*)d_ws + (4u << 20));    // [T,8]   96 MB
    int*   kjp      = (int*)((char*)d_ws + (102u << 20));    // [T]     12 MB
    float* re1      = (float*)((char*)d_ws + (116u << 20));  // [E,8]  9.6 MB
    char*  wimg     = (char*)d_ws + (130u << 20);            // 640 KB weight images

    char* wkj_i  = wimg;
    char* wji_i  = wimg + 65536;
    char* wdn_i  = wimg + 131072;
    char* wup_i  = wimg + 163840;
    char* r1w1_i = wimg + 196608;
    char* r1w2_i = wimg + 262144;
    char* wbs_i  = wimg + 327680;
    char* r2w1_i = wimg + 393216;
    char* r2w2_i = wimg + 458752;
    char* r3w1_i = wimg + 524288;
    char* r3w2_i = wimg + 589824;

    WPrepArgs pa;
    pa.w[0]  = {w_kj,   wkj_i,  128, 128};
    pa.w[1]  = {w_ji,   wji_i,  128, 128};
    pa.w[2]  = {w_down, wdn_i,  128,  64};
    pa.w[3]  = {w_up,   wup_i,   64, 128};
    pa.w[4]  = {r1w1,   r1w1_i, 128, 128};
    pa.w[5]  = {r1w2,   r1w2_i, 128, 128};
    pa.w[6]  = {w_bs,   wbs_i,  128, 128};
    pa.w[7]  = {r2w1,   r2w1_i, 128, 128};
    pa.w[8]  = {r2w2,   r2w2_i, 128, 128};
    pa.w[9]  = {r3w1,   r3w1_i, 128, 128};
    pa.w[10] = {r3w2,   r3w2_i, 128, 128};

    const dim3 b256(256);
    const int gB  = (E + 63) / 64;
    const int gT  = (T + 255) / 256;
    const int NB  = (E + 1023) / 1024;
    const int gE4 = (E + 3) / 4;
    const int gR  = (E * 8 + 255) / 256;

    // weight prep + prologue + CSR
    wprep_kernel<<<dim3(4, 11), b256, 0, stream>>>(pa);
    rbf1_kernel<<<gR, b256, 0, stream>>>(rbf, w_rbf1, re1, E);
    hipMemsetAsync(cnt, 0, (size_t)E * 4, stream);
    count_kernel<<<gT, b256, 0, stream>>>(idx_ji, cnt, T);
    scan_partial_kernel<<<NB, b256, 0, stream>>>(cnt, partial, E);
    scan_block_kernel<<<1, b256, 0, stream>>>(partial, blockoff, NB, offsets, E);
    scan_final_kernel<<<NB, b256, 0, stream>>>(cnt, blockoff, offsets, cnt, E);
    e1fill_kernel<<<gT, b256, 0, stream>>>(sbf, w_sbf1, idx_ji, idx_kj, cnt, E1p, kjp, T);

    // K1: x -> W3
    k1_kernel<<<gB, b256, 0, stream>>>(x, wkj_i, b_kj, re1, w_rbf2, wdn_i, W3, E);
    // gather -> W4
    gather_kernel<<<gE4, b256, 0, stream>>>(E1p, kjp, w_sbf2, offsets, W3, W4, E);
    // K4: x, W4 -> h0 (in d_out)
    k4_kernel<<<gB, b256, 0, stream>>>(x, wji_i, b_ji, W4, wup_i, OUT, E);
    // K5: res1 + w_bs + skip, in-place on d_out
    k5_kernel<<<gB, b256, 0, stream>>>(OUT, x, r1w1_i, r1b1, r1w2_i, r1b2, wbs_i, b_bs, E);
    // res blocks, in-place
    res_kernel<<<gB, b256, 0, stream>>>(OUT, r2w1_i, r2b1, r2w2_i, r2b2, E);
    res_kernel<<<gB, b256, 0, stream>>>(OUT, r3w1_i, r3b1, r3w2_i, r3b2, E);
}

// Round 8
// 1249.882 us; speedup vs baseline: 1.3097x; 1.0282x over previous
//
#include <hip/hip_runtime.h>

// ---------------------------------------------------------------------------
// DimeNet++ interaction block, round 8:
//   - e1fill: LDS-staged coalesced sbf reads, NO atomics (rank precomputed
//     as the atomicAdd return value inside count_kernel)
//   - post-gather chain fused into ONE kernel (kbig): 9 GEMMs row-local,
//     h0/h2/h3 in registers, activations bounce through t_lds only
// ---------------------------------------------------------------------------

typedef __attribute__((ext_vector_type(8))) short bf16x8;
typedef __attribute__((ext_vector_type(4))) float f32x4;

__device__ __forceinline__ float silu_f(float v) { return v / (1.0f + __expf(-v)); }
__device__ __forceinline__ short f2bf(float f) {
    unsigned u = __float_as_uint(f);
    unsigned r = u + 0x7fffu + ((u >> 16) & 1u);
    return (short)(r >> 16);
}
__device__ __forceinline__ float bf2f(short s) {
    return __uint_as_float(((unsigned)(unsigned short)s) << 16);
}
__device__ __forceinline__ void split44(f32x4 a, f32x4 b, bf16x8& hi, bf16x8& lo) {
    #pragma unroll
    for (int j = 0; j < 4; ++j) { short h = f2bf(a[j]); hi[j] = h; lo[j] = f2bf(a[j] - bf2f(h)); }
    #pragma unroll
    for (int j = 0; j < 4; ++j) { short h = f2bf(b[j]); hi[4 + j] = h; lo[4 + j] = f2bf(b[j] - bf2f(h)); }
}

__device__ __forceinline__ void gll16(const void* g, void* l) {
    __builtin_amdgcn_global_load_lds((const __attribute__((address_space(1))) void*)g,
                                     (__attribute__((address_space(3))) void*)l, 16, 0, 0);
}
__device__ __forceinline__ void stage16(const char* g, short* l, int lane, int wid) {
    #pragma unroll
    for (int i = 0; i < 4; ++i) {
        const int off = ((i * 4 + wid) << 10);
        gll16(g + off + lane * 16, (char*)l + off);
    }
}
__device__ __forceinline__ void stage8(const char* g, short* l, int lane, int wid) {
    #pragma unroll
    for (int i = 0; i < 2; ++i) {
        const int off = ((i * 4 + wid) << 10);
        gll16(g + off + lane * 16, (char*)l + off);
    }
}

template<int NF>
__device__ __forceinline__ void mfma_ks(bf16x8 ah, bf16x8 al, const short* slot,
                                        int acol, int kq, f32x4* acc) {
    #pragma unroll
    for (int n = 0; n < NF; ++n) {
        const int c = n * 16 + acol;
        const int x = (c >> 2) & 1;
        const int sw = (kq ^ (c & 3)) << 3;
        const bf16x8 bh = *(const bf16x8*)&slot[c * 64 + x * 32 + sw];
        const bf16x8 bl = *(const bf16x8*)&slot[c * 64 + (x ^ 1) * 32 + sw];
        acc[n] = __builtin_amdgcn_mfma_f32_16x16x32_bf16(ah, bh, acc[n], 0, 0, 0);
        acc[n] = __builtin_amdgcn_mfma_f32_16x16x32_bf16(al, bh, acc[n], 0, 0, 0);
        acc[n] = __builtin_amdgcn_mfma_f32_16x16x32_bf16(ah, bl, acc[n], 0, 0, 0);
    }
}
template<int NF>
__device__ __forceinline__ void gphase(f32x4 a0, f32x4 a1, const short* slot,
                                       int acol, int kq, f32x4* acc) {
    bf16x8 ah, al; split44(a0, a1, ah, al);
    mfma_ks<NF>(ah, al, slot, acol, kq, acc);
}
template<int NF>
__device__ __forceinline__ void tphase(const float* tl, int rowbase, int q,
                                       int kq, int acol, const short* slot, f32x4* acc) {
    const f32x4 ta = *(const f32x4*)&tl[rowbase + q * 32 + kq * 8];
    const f32x4 tb = *(const f32x4*)&tl[rowbase + q * 32 + kq * 8 + 4];
    bf16x8 ah, al; split44(ta, tb, ah, al);
    mfma_ks<NF>(ah, al, slot, acol, kq, acc);
}

// 4-phase 128x128 GEMM from t_lds; pre: slotA holds img slab0; post: imgnext
// slab0 staged into slotA (if non-null).
__device__ __forceinline__ void tgemm4(const char* img, const char* imgnext,
                                       short* sA, short* sB, const float* tl, int rb,
                                       int kq, int acol, int lane, int wid, f32x4* acc)
{
    stage16(img + 16384, sB, lane, wid);
    tphase<8>(tl, rb, 0, kq, acol, sA, acc); __syncthreads();
    stage16(img + 32768, sA, lane, wid);
    tphase<8>(tl, rb, 1, kq, acol, sB, acc); __syncthreads();
    stage16(img + 49152, sB, lane, wid);
    tphase<8>(tl, rb, 2, kq, acol, sA, acc); __syncthreads();
    if (imgnext) stage16(imgnext, sA, lane, wid);
    tphase<8>(tl, rb, 3, kq, acol, sB, acc); __syncthreads();
}

#define TPITCH 132

// ---------------- weight pre-conversion -------------------------------------
struct WDesc { const float* src; char* dst; int K; int N; };
struct WPrepArgs { WDesc w[11]; };

__global__ void wprep_kernel(WPrepArgs args) {
    const WDesc d = args.w[blockIdx.y];
    const int h = blockIdx.x;
    if (h * 32 >= d.K) return;
    char* slab = d.dst + (size_t)h * d.N * 128;
    for (int idx = threadIdx.x; idx < d.N * 4; idx += 256) {
        const int c = idx >> 2, ch = idx & 3;
        bf16x8 hi, lo;
        #pragma unroll
        for (int j = 0; j < 8; ++j) {
            const float f = d.src[(size_t)(h * 32 + ch * 8 + j) * d.N + c];
            const short hb = f2bf(f);
            hi[j] = hb;
            lo[j] = f2bf(f - bf2f(hb));
        }
        const int x = (c >> 2) & 1;
        const int sw = (ch ^ (c & 3)) * 16;
        *(bf16x8*)(slab + c * 128 + x * 64 + sw)       = hi;
        *(bf16x8*)(slab + c * 128 + (x ^ 1) * 64 + sw) = lo;
    }
}

// ---------------- prologue / CSR --------------------------------------------

__global__ void rbf1_kernel(const float* __restrict__ rbf, const float* __restrict__ w_rbf1,
                            float* __restrict__ re1, int E) {
    const int i = blockIdx.x * 256 + threadIdx.x;
    const int e = i >> 3, p = i & 7;
    if (e < E) {
        float s = 0.f;
        #pragma unroll
        for (int q = 0; q < 6; ++q) s = fmaf(rbf[e * 6 + q], w_rbf1[q * 8 + p], s);
        re1[i] = s;
    }
}

// histogram of idx_ji; also records each triplet's arrival rank within its bin
__global__ void count_rank_kernel(const int* __restrict__ idx_ji, int* __restrict__ cnt,
                                  int* __restrict__ rank, int T) {
    const int i = (blockIdx.x * 256 + threadIdx.x) * 4;
    if (i + 3 < T) {
        const int4 j = *(const int4*)&idx_ji[i];
        int4 r;
        r.x = atomicAdd(&cnt[j.x], 1);
        r.y = atomicAdd(&cnt[j.y], 1);
        r.z = atomicAdd(&cnt[j.z], 1);
        r.w = atomicAdd(&cnt[j.w], 1);
        *(int4*)&rank[i] = r;
    } else {
        for (int k = i; k < T; ++k) rank[k] = atomicAdd(&cnt[idx_ji[k]], 1);
    }
}

__global__ void scan_partial_kernel(const int* __restrict__ cnt, int* __restrict__ partial, int E) {
    __shared__ int red[256];
    const int tid = threadIdx.x;
    const int base = blockIdx.x * 1024 + tid * 4;
    int s = 0;
    #pragma unroll
    for (int i = 0; i < 4; ++i) { const int g = base + i; if (g < E) s += cnt[g]; }
    red[tid] = s;
    __syncthreads();
    for (int off = 128; off > 0; off >>= 1) {
        if (tid < off) red[tid] += red[tid + off];
        __syncthreads();
    }
    if (tid == 0) partial[blockIdx.x] = red[0];
}

__global__ void scan_block_kernel(const int* __restrict__ partial, int* __restrict__ blockoff,
                                  int NB, int* offsets, int E) {
    __shared__ int red[256];
    const int tid = threadIdx.x;
    int v[4]; int s = 0;
    #pragma unroll
    for (int i = 0; i < 4; ++i) { const int g = tid * 4 + i; v[i] = (g < NB) ? partial[g] : 0; s += v[i]; }
    red[tid] = s;
    __syncthreads();
    for (int off = 1; off < 256; off <<= 1) {
        const int add = (tid >= off) ? red[tid - off] : 0;
        __syncthreads();
        red[tid] += add;
        __syncthreads();
    }
    int excl = (tid == 0) ? 0 : red[tid - 1];
    #pragma unroll
    for (int i = 0; i < 4; ++i) { const int g = tid * 4 + i; if (g < NB) blockoff[g] = excl; excl += v[i]; }
    if (tid == 255) offsets[E] = red[255];
}

__global__ void scan_final_kernel(const int* __restrict__ cnt, const int* __restrict__ blockoff,
                                  int* __restrict__ offsets, int E) {
    __shared__ int red[256];
    const int tid = threadIdx.x;
    const int base = blockIdx.x * 1024 + tid * 4;
    int v[4]; int s = 0;
    #pragma unroll
    for (int i = 0; i < 4; ++i) { const int g = base + i; v[i] = (g < E) ? cnt[g] : 0; s += v[i]; }
    red[tid] = s;
    __syncthreads();
    for (int off = 1; off < 256; off <<= 1) {
        const int add = (tid >= off) ? red[tid - off] : 0;
        __syncthreads();
        red[tid] += add;
        __syncthreads();
    }
    int run = blockoff[blockIdx.x] + ((tid == 0) ? 0 : red[tid - 1]);
    #pragma unroll
    for (int i = 0; i < 4; ++i) {
        const int g = base + i;
        if (g < E) offsets[g] = run;
        run += v[i];
    }
}

// e1 projection + CSR placement, atomic-free (pos = offsets[ji] + rank[t]).
// sbf block staged via coalesced float4 into pitch-43 LDS (2-way-free reads).
__launch_bounds__(256, 3)
__global__ void e1fill_kernel(const float* __restrict__ sbf, const float* __restrict__ w_sbf1,
                              const int* __restrict__ idx_ji, const int* __restrict__ idx_kj,
                              const int* __restrict__ rank, const int* __restrict__ offsets,
                              float* __restrict__ E1p, int* __restrict__ kjp, int T)
{
    __shared__ float s_lds[256 * 43];
    const int tid = threadIdx.x;
    const long long t0 = (long long)blockIdx.x * 256;
    const int nrow = min(256, (int)(T - t0));
    const int nel  = nrow * 42;
    const float* base = sbf + t0 * 42;

    for (int i = tid * 4; i + 3 < nel; i += 1024) {
        const float4 v = *(const float4*)&base[i];
        s_lds[(i + 0) + (i + 0) / 42] = v.x;
        s_lds[(i + 1) + (i + 1) / 42] = v.y;
        s_lds[(i + 2) + (i + 2) / 42] = v.z;
        s_lds[(i + 3) + (i + 3) / 42] = v.w;
    }
    const int tail0 = nel & ~3;
    if (tid < nel - tail0) { const int g = tail0 + tid; s_lds[g + g / 42] = base[g]; }
    __syncthreads();

    const int t = (int)t0 + tid;
    if (t >= T) return;
    const float* srow = &s_lds[tid * 43];
    float e1[8] = {0.f, 0.f, 0.f, 0.f, 0.f, 0.f, 0.f, 0.f};
    #pragma unroll
    for (int q = 0; q < 42; ++q) {
        const float s = srow[q];
        #pragma unroll
        for (int p = 0; p < 8; ++p) e1[p] = fmaf(s, w_sbf1[q * 8 + p], e1[p]);
    }
    const int ji  = idx_ji[t];
    const int pos = offsets[ji] + rank[t];
    *(float4*)&E1p[(size_t)pos * 8]     = *(float4*)&e1[0];
    *(float4*)&E1p[(size_t)pos * 8 + 4] = *(float4*)&e1[4];
    kjp[pos] = idx_kj[t];
}

__launch_bounds__(256, 4)
__global__ void gather_kernel(const float* __restrict__ E1p, const int* __restrict__ kjp,
                              const float* __restrict__ w_sbf2, const int* __restrict__ offsets,
                              const float* __restrict__ xkjd, float* __restrict__ agg, int E)
{
    const int tid  = threadIdx.x;
    const int lane = tid & 63;
    const int e    = blockIdx.x * 4 + (tid >> 6);

    float w2[8];
    #pragma unroll
    for (int p = 0; p < 8; ++p) w2[p] = w_sbf2[p * 64 + lane];

    if (e >= E) return;
    const int j0 = __builtin_amdgcn_readfirstlane(offsets[e]);
    const int j1 = __builtin_amdgcn_readfirstlane(offsets[e + 1]);

    float acc = 0.f;
    if (j0 < j1) {
        int kj = __builtin_amdgcn_readfirstlane(kjp[j0]);
        float4 ea = *(const float4*)&E1p[(size_t)j0 * 8];
        float4 eb = *(const float4*)&E1p[(size_t)j0 * 8 + 4];
        for (int j = j0; j < j1; ++j) {
            const float xv = xkjd[(size_t)kj * 64 + lane];
            int kn = 0; float4 ean = {}, ebn = {};
            if (j + 1 < j1) {
                kn  = __builtin_amdgcn_readfirstlane(kjp[j + 1]);
                ean = *(const float4*)&E1p[(size_t)(j + 1) * 8];
                ebn = *(const float4*)&E1p[(size_t)(j + 1) * 8 + 4];
            }
            float sv = ea.x * w2[0];
            sv = fmaf(ea.y, w2[1], sv);
            sv = fmaf(ea.z, w2[2], sv);
            sv = fmaf(ea.w, w2[3], sv);
            sv = fmaf(eb.x, w2[4], sv);
            sv = fmaf(eb.y, w2[5], sv);
            sv = fmaf(eb.z, w2[6], sv);
            sv = fmaf(eb.w, w2[7], sv);
            acc = fmaf(xv, sv, acc);
            kj = kn; ea = ean; eb = ebn;
        }
    }
    agg[(size_t)e * 64 + lane] = acc;
}

// ---------------- K1: W3 = silu((silu(x@w_kj+b)*rbf_e)@w_down) --------------
__launch_bounds__(256, 2)
__global__ void k1_kernel(const float* __restrict__ x, const char* __restrict__ wkj_i,
                          const float* __restrict__ b_kj, const float* __restrict__ re1,
                          const float* __restrict__ w_rbf2, const char* __restrict__ wdn_i,
                          float* __restrict__ W3, int E)
{
    __shared__ short slotA[8192], slotB[8192];
    __shared__ float t_lds[64 * TPITCH];
    __shared__ float w2_lds[8 * 128];
    const int tid = threadIdx.x, lane = tid & 63, wid = tid >> 6;
    const int acol = lane & 15, kq = lane >> 4;
    const int rowW = blockIdx.x * 64 + wid * 16;
    const int arow = rowW + acol;
    const bool av = arow < E;

    stage16(wkj_i, slotA, lane, wid);
    const float* xr = x + (size_t)arow * 128;
    f32x4 a[4][2];
    #pragma unroll
    for (int ks = 0; ks < 4; ++ks) {
        a[ks][0] = f32x4{0.f, 0.f, 0.f, 0.f}; a[ks][1] = f32x4{0.f, 0.f, 0.f, 0.f};
        if (av) { a[ks][0] = *(const f32x4*)&xr[ks * 32 + kq * 8];
                  a[ks][1] = *(const f32x4*)&xr[ks * 32 + kq * 8 + 4]; }
    }
    float bv[8];
    #pragma unroll
    for (int n = 0; n < 8; ++n) bv[n] = b_kj[n * 16 + acol];
    f32x4 e1a[4], e1b[4];
    #pragma unroll
    for (int r = 0; r < 4; ++r) {
        const int ge = rowW + kq * 4 + r;
        e1a[r] = f32x4{0.f, 0.f, 0.f, 0.f}; e1b[r] = f32x4{0.f, 0.f, 0.f, 0.f};
        if (ge < E) { e1a[r] = *(const f32x4*)&re1[(size_t)ge * 8];
                      e1b[r] = *(const f32x4*)&re1[(size_t)ge * 8 + 4]; }
    }
    for (int i = tid; i < 1024; i += 256) w2_lds[i] = w_rbf2[i];
    __syncthreads();

    f32x4 acc[8];
    #pragma unroll
    for (int n = 0; n < 8; ++n) acc[n] = f32x4{0.f, 0.f, 0.f, 0.f};

    stage16(wkj_i + 16384, slotB, lane, wid);
    gphase<8>(a[0][0], a[0][1], slotA, acol, kq, acc); __syncthreads();
    stage16(wkj_i + 32768, slotA, lane, wid);
    gphase<8>(a[1][0], a[1][1], slotB, acol, kq, acc); __syncthreads();
    stage16(wkj_i + 49152, slotB, lane, wid);
    gphase<8>(a[2][0], a[2][1], slotA, acol, kq, acc); __syncthreads();
    stage8(wdn_i, slotA, lane, wid);
    gphase<8>(a[3][0], a[3][1], slotB, acol, kq, acc); __syncthreads();

    #pragma unroll
    for (int n = 0; n < 8; ++n) {
        const int c = n * 16 + acol;
        float w2c[8];
        #pragma unroll
        for (int p = 0; p < 8; ++p) w2c[p] = w2_lds[p * 128 + c];
        #pragma unroll
        for (int r = 0; r < 4; ++r) {
            float s = e1a[r][0] * w2c[0];
            s = fmaf(e1a[r][1], w2c[1], s);
            s = fmaf(e1a[r][2], w2c[2], s);
            s = fmaf(e1a[r][3], w2c[3], s);
            s = fmaf(e1b[r][0], w2c[4], s);
            s = fmaf(e1b[r][1], w2c[5], s);
            s = fmaf(e1b[r][2], w2c[6], s);
            s = fmaf(e1b[r][3], w2c[7], s);
            t_lds[(wid * 16 + kq * 4 + r) * TPITCH + c] = silu_f(acc[n][r] + bv[n]) * s;
        }
    }
    __syncthreads();

    f32x4 acc2[4];
    #pragma unroll
    for (int n = 0; n < 4; ++n) acc2[n] = f32x4{0.f, 0.f, 0.f, 0.f};
    const int rb = (wid * 16 + acol) * TPITCH;

    stage8(wdn_i + 8192, slotB, lane, wid);
    tphase<4>(t_lds, rb, 0, kq, acol, slotA, acc2); __syncthreads();
    stage8(wdn_i + 16384, slotA, lane, wid);
    tphase<4>(t_lds, rb, 1, kq, acol, slotB, acc2); __syncthreads();
    stage8(wdn_i + 24576, slotB, lane, wid);
    tphase<4>(t_lds, rb, 2, kq, acol, slotA, acc2); __syncthreads();
    tphase<4>(t_lds, rb, 3, kq, acol, slotB, acc2);

    #pragma unroll
    for (int n = 0; n < 4; ++n) {
        const int c = n * 16 + acol;
        #pragma unroll
        for (int r = 0; r < 4; ++r) {
            const int ge = rowW + kq * 4 + r;
            if (ge < E) W3[(size_t)ge * 64 + c] = silu_f(acc2[n][r]);
        }
    }
}

// ---------------- kbig: h0 -> res1 -> w_bs+skip -> res2 -> res3 (9 GEMMs) ---
struct KBigArgs {
    const float* x; const float* W4; float* out;
    const char *wji, *wup, *r1w1, *r1w2, *wbs, *r2w1, *r2w2, *r3w1, *r3w2;
    const float *bji, *r1b1, *r1b2, *bbs, *r2b1, *r2b2, *r3b1, *r3b2;
    int E;
};

__launch_bounds__(256, 2)
__global__ void kbig_kernel(KBigArgs A_)
{
    __shared__ short slotA[8192], slotB[8192];
    __shared__ float t_lds[64 * TPITCH];
    const int tid = threadIdx.x, lane = tid & 63, wid = tid >> 6;
    const int acol = lane & 15, kq = lane >> 4;
    const int rowW = blockIdx.x * 64 + wid * 16;
    const int arow = rowW + acol;
    const int E = A_.E;
    const bool av = arow < E;
    const int rb = (wid * 16 + acol) * TPITCH;

    stage16(A_.wji, slotA, lane, wid);

    const float* xr = A_.x + (size_t)arow * 128;
    const float* wr = A_.W4 + (size_t)arow * 64;
    f32x4 a[4][2], u[2][2];
    #pragma unroll
    for (int ks = 0; ks < 4; ++ks) {
        a[ks][0] = f32x4{0.f, 0.f, 0.f, 0.f}; a[ks][1] = f32x4{0.f, 0.f, 0.f, 0.f};
        if (av) { a[ks][0] = *(const f32x4*)&xr[ks * 32 + kq * 8];
                  a[ks][1] = *(const f32x4*)&xr[ks * 32 + kq * 8 + 4]; }
    }
    #pragma unroll
    for (int ks = 0; ks < 2; ++ks) {
        u[ks][0] = f32x4{0.f, 0.f, 0.f, 0.f}; u[ks][1] = f32x4{0.f, 0.f, 0.f, 0.f};
        if (av) { u[ks][0] = *(const f32x4*)&wr[ks * 32 + kq * 8];
                  u[ks][1] = *(const f32x4*)&wr[ks * 32 + kq * 8 + 4]; }
    }
    __syncthreads();

    f32x4 acc[8];
    #pragma unroll
    for (int n = 0; n < 8; ++n) acc[n] = f32x4{0.f, 0.f, 0.f, 0.f};

    // GEMM1: x @ w_ji
    stage16(A_.wji + 16384, slotB, lane, wid);
    gphase<8>(a[0][0], a[0][1], slotA, acol, kq, acc); __syncthreads();
    stage16(A_.wji + 32768, slotA, lane, wid);
    gphase<8>(a[1][0], a[1][1], slotB, acol, kq, acc); __syncthreads();
    stage16(A_.wji + 49152, slotB, lane, wid);
    gphase<8>(a[2][0], a[2][1], slotA, acol, kq, acc); __syncthreads();
    stage16(A_.wup, slotA, lane, wid);
    gphase<8>(a[3][0], a[3][1], slotB, acol, kq, acc); __syncthreads();

    float res[8][4];
    #pragma unroll
    for (int n = 0; n < 8; ++n) {
        const float bv = A_.bji[n * 16 + acol];
        #pragma unroll
        for (int r = 0; r < 4; ++r) { res[n][r] = silu_f(acc[n][r] + bv); acc[n][r] = 0.f; }
    }

    // GEMM2: W4 @ w_up (K=64)
    stage16(A_.wup + 16384, slotB, lane, wid);
    gphase<8>(u[0][0], u[0][1], slotA, acol, kq, acc); __syncthreads();
    stage16(A_.r1w1, slotA, lane, wid);
    gphase<8>(u[1][0], u[1][1], slotB, acol, kq, acc); __syncthreads();

    #pragma unroll
    for (int n = 0; n < 8; ++n) {
        const int c = n * 16 + acol;
        #pragma unroll
        for (int r = 0; r < 4; ++r) {
            res[n][r] += silu_f(acc[n][r]);                     // h0
            t_lds[(wid * 16 + kq * 4 + r) * TPITCH + c] = res[n][r];
            acc[n][r] = 0.f;
        }
    }
    __syncthreads();

    // GEMM3: h0 @ r1w1 -> t1
    tgemm4(A_.r1w1, A_.r1w2, slotA, slotB, t_lds, rb, kq, acol, lane, wid, acc);
    #pragma unroll
    for (int n = 0; n < 8; ++n) {
        const float bv = A_.r1b1[n * 16 + acol];
        const int c = n * 16 + acol;
        #pragma unroll
        for (int r = 0; r < 4; ++r) {
            t_lds[(wid * 16 + kq * 4 + r) * TPITCH + c] = silu_f(acc[n][r] + bv);
            acc[n][r] = 0.f;
        }
    }
    __syncthreads();

    // GEMM4: t1 @ r1w2 -> t2 = h0 + silu(.)
    tgemm4(A_.r1w2, A_.wbs, slotA, slotB, t_lds, rb, kq, acol, lane, wid, acc);
    #pragma unroll
    for (int n = 0; n < 8; ++n) {
        const float bv = A_.r1b2[n * 16 + acol];
        const int c = n * 16 + acol;
        #pragma unroll
        for (int r = 0; r < 4; ++r) {
            t_lds[(wid * 16 + kq * 4 + r) * TPITCH + c] = res[n][r] + silu_f(acc[n][r] + bv);
            acc[n][r] = 0.f;
        }
    }
    __syncthreads();

    // GEMM5: t2 @ w_bs -> h2 = silu(.) + x
    tgemm4(A_.wbs, A_.r2w1, slotA, slotB, t_lds, rb, kq, acol, lane, wid, acc);
    #pragma unroll
    for (int n = 0; n < 8; ++n) {
        const float bv = A_.bbs[n * 16 + acol];
        const int c = n * 16 + acol;
        #pragma unroll
        for (int r = 0; r < 4; ++r) {
            const int ge = rowW + kq * 4 + r;
            const float xv = (ge < E) ? A_.x[(size_t)ge * 128 + c] : 0.f;
            res[n][r] = silu_f(acc[n][r] + bv) + xv;            // h2
            t_lds[(wid * 16 + kq * 4 + r) * TPITCH + c] = res[n][r];
            acc[n][r] = 0.f;
        }
    }
    __syncthreads();

    // GEMM6: h2 @ r2w1 -> t3
    tgemm4(A_.r2w1, A_.r2w2, slotA, slotB, t_lds, rb, kq, acol, lane, wid, acc);
    #pragma unroll
    for (int n = 0; n < 8; ++n) {
        const float bv = A_.r2b1[n * 16 + acol];
        const int c = n * 16 + acol;
        #pragma unroll
        for (int r = 0; r < 4; ++r) {
            t_lds[(wid * 16 + kq * 4 + r) * TPITCH + c] = silu_f(acc[n][r] + bv);
            acc[n][r] = 0.f;
        }
    }
    __syncthreads();

    // GEMM7: t3 @ r2w2 -> h3 = h2 + silu(.)
    tgemm4(A_.r2w2, A_.r3w1, slotA, slotB, t_lds, rb, kq, acol, lane, wid, acc);
    #pragma unroll
    for (int n = 0; n < 8; ++n) {
        const float bv = A_.r2b2[n * 16 + acol];
        const int c = n * 16 + acol;
        #pragma unroll
        for (int r = 0; r < 4; ++r) {
            res[n][r] += silu_f(acc[n][r] + bv);                // h3
            t_lds[(wid * 16 + kq * 4 + r) * TPITCH + c] = res[n][r];
            acc[n][r] = 0.f;
        }
    }
    __syncthreads();

    // GEMM8: h3 @ r3w1 -> t4
    tgemm4(A_.r3w1, A_.r3w2, slotA, slotB, t_lds, rb, kq, acol, lane, wid, acc);
    #pragma unroll
    for (int n = 0; n < 8; ++n) {
        const float bv = A_.r3b1[n * 16 + acol];
        const int c = n * 16 + acol;
        #pragma unroll
        for (int r = 0; r < 4; ++r) {
            t_lds[(wid * 16 + kq * 4 + r) * TPITCH + c] = silu_f(acc[n][r] + bv);
            acc[n][r] = 0.f;
        }
    }
    __syncthreads();

    // GEMM9: t4 @ r3w2 -> out = h3 + silu(.)
    tgemm4(A_.r3w2, nullptr, slotA, slotB, t_lds, rb, kq, acol, lane, wid, acc);
    #pragma unroll
    for (int n = 0; n < 8; ++n) {
        const float bv = A_.r3b2[n * 16 + acol];
        const int c = n * 16 + acol;
        #pragma unroll
        for (int r = 0; r < 4; ++r) {
            const int ge = rowW + kq * 4 + r;
            if (ge < E)
                A_.out[(size_t)ge * 128 + c] = res[n][r] + silu_f(acc[n][r] + bv);
        }
    }
}

// ---------------------------------------------------------------------------

extern "C" void kernel_launch(void* const* d_in, const int* in_sizes, int n_in,
                              void* d_out, int out_size, void* d_ws, size_t ws_size,
                              hipStream_t stream)
{
    const float* x      = (const float*)d_in[0];
    const float* rbf    = (const float*)d_in[1];
    const float* sbf    = (const float*)d_in[2];
    const int*   idx_kj = (const int*)d_in[3];
    const int*   idx_ji = (const int*)d_in[4];
    const float* w_rbf1 = (const float*)d_in[5];
    const float* w_rbf2 = (const float*)d_in[6];
    const float* w_sbf1 = (const float*)d_in[7];
    const float* w_sbf2 = (const float*)d_in[8];
    const float* w_kj   = (const float*)d_in[9];
    const float* b_kj   = (const float*)d_in[10];
    const float* w_ji   = (const float*)d_in[11];
    const float* b_ji   = (const float*)d_in[12];
    const float* w_down = (const float*)d_in[13];
    const float* w_up   = (const float*)d_in[14];
    const float* r1w1   = (const float*)d_in[15];
    const float* r1b1   = (const float*)d_in[16];
    const float* r1w2   = (const float*)d_in[17];
    const float* r1b2   = (const float*)d_in[18];
    const float* w_bs   = (const float*)d_in[19];
    const float* b_bs   = (const float*)d_in[20];
    const float* r2w1   = (const float*)d_in[21];
    const float* r2b1   = (const float*)d_in[22];
    const float* r2w2   = (const float*)d_in[23];
    const float* r2b2   = (const float*)d_in[24];
    const float* r3w1   = (const float*)d_in[25];
    const float* r3b1   = (const float*)d_in[26];
    const float* r3w2   = (const float*)d_in[27];
    const float* r3b2   = (const float*)d_in[28];

    const int E = in_sizes[0] / 128;
    const int T = in_sizes[2] / 42;

    float* OUT = (float*)d_out;
    float* W3  = (float*)((char*)d_ws + (size_t)E * 128 * 4);         // [E,64]
    float* W4  = (float*)((char*)d_ws + (size_t)E * 128 * 4
                                      + (size_t)E * 64 * 4);          // [E,64]

    // scratch overlays in [0, E*128*4):
    int*   cnt      = (int*)d_ws;                            // [E]
    int*   offsets  = cnt + (E + 64);                        // [E+1]
    int*   partial  = offsets + (E + 64);                    // [<=1024]
    int*   blockoff = partial + 1024;                        // [<=1024]
    float* E1p      = (float*)((char*)d_ws + (4u << 20));    // [T,8]   96 MB
    int*   kjp      = (int*)((char*)d_ws + (102u << 20));    // [T]     12 MB
    float* re1      = (float*)((char*)d_ws + (116u << 20));  // [E,8]  9.6 MB
    char*  wimg     = (char*)d_ws + (130u << 20);            // 640 KB
    int*   rank     = (int*)((char*)d_ws + (134u << 20));    // [T]     12 MB

    char* wkj_i  = wimg;
    char* wji_i  = wimg + 65536;
    char* wdn_i  = wimg + 131072;
    char* wup_i  = wimg + 163840;
    char* r1w1_i = wimg + 196608;
    char* r1w2_i = wimg + 262144;
    char* wbs_i  = wimg + 327680;
    char* r2w1_i = wimg + 393216;
    char* r2w2_i = wimg + 458752;
    char* r3w1_i = wimg + 524288;
    char* r3w2_i = wimg + 589824;

    WPrepArgs pa;
    pa.w[0]  = {w_kj,   wkj_i,  128, 128};
    pa.w[1]  = {w_ji,   wji_i,  128, 128};
    pa.w[2]  = {w_down, wdn_i,  128,  64};
    pa.w[3]  = {w_up,   wup_i,   64, 128};
    pa.w[4]  = {r1w1,   r1w1_i, 128, 128};
    pa.w[5]  = {r1w2,   r1w2_i, 128, 128};
    pa.w[6]  = {w_bs,   wbs_i,  128, 128};
    pa.w[7]  = {r2w1,   r2w1_i, 128, 128};
    pa.w[8]  = {r2w2,   r2w2_i, 128, 128};
    pa.w[9]  = {r3w1,   r3w1_i, 128, 128};
    pa.w[10] = {r3w2,   r3w2_i, 128, 128};

    const dim3 b256(256);
    const int gB  = (E + 63) / 64;
    const int gT  = (T + 255) / 256;
    const int gT4 = (T + 1023) / 1024;
    const int NB  = (E + 1023) / 1024;
    const int gE4 = (E + 3) / 4;
    const int gR  = (E * 8 + 255) / 256;

    wprep_kernel<<<dim3(4, 11), b256, 0, stream>>>(pa);
    rbf1_kernel<<<gR, b256, 0, stream>>>(rbf, w_rbf1, re1, E);
    hipMemsetAsync(cnt, 0, (size_t)E * 4, stream);
    count_rank_kernel<<<gT4, b256, 0, stream>>>(idx_ji, cnt, rank, T);
    scan_partial_kernel<<<NB, b256, 0, stream>>>(cnt, partial, E);
    scan_block_kernel<<<1, b256, 0, stream>>>(partial, blockoff, NB, offsets, E);
    scan_final_kernel<<<NB, b256, 0, stream>>>(cnt, blockoff, offsets, E);
    e1fill_kernel<<<gT, b256, 0, stream>>>(sbf, w_sbf1, idx_ji, idx_kj, rank, offsets, E1p, kjp, T);

    k1_kernel<<<gB, b256, 0, stream>>>(x, wkj_i, b_kj, re1, w_rbf2, wdn_i, W3, E);
    gather_kernel<<<gE4, b256, 0, stream>>>(E1p, kjp, w_sbf2, offsets, W3, W4, E);

    KBigArgs ka;
    ka.x = x; ka.W4 = W4; ka.out = OUT;
    ka.wji = wji_i; ka.wup = wup_i; ka.r1w1 = r1w1_i; ka.r1w2 = r1w2_i; ka.wbs = wbs_i;
    ka.r2w1 = r2w1_i; ka.r2w2 = r2w2_i; ka.r3w1 = r3w1_i; ka.r3w2 = r3w2_i;
    ka.bji = b_ji; ka.r1b1 = r1b1; ka.r1b2 = r1b2; ka.bbs = b_bs;
    ka.r2b1 = r2b1; ka.r2b2 = r2b2; ka.r3b1 = r3b1; ka.r3b2 = r3b2;
    ka.E = E;
    kbig_kernel<<<gB, b256, 0, stream>>>(ka);
}

// Round 9
// 1199.416 us; speedup vs baseline: 1.3648x; 1.0421x over previous
//
#include <hip/hip_runtime.h>
#include <hip/hip_bf16.h>

// ---------------------------------------------------------------------------
// DimeNet++ interaction block, round 9:
//   - fp32->bf16 hi/lo split via v_cvt_pk_bf16_f32 (native packed cvt, RNE):
//     ~3 VALU ops/float instead of ~11 (kbig was VALU-bound at 49.6%)
//   - silu via hardware rcp
//   - structure identical to round 8 (CSR rank trick, fused kbig, k1, gather)
// ---------------------------------------------------------------------------

typedef __attribute__((ext_vector_type(8))) short bf16x8;
typedef __attribute__((ext_vector_type(4))) float f32x4;
typedef __attribute__((ext_vector_type(4))) unsigned int u32x4;

__device__ __forceinline__ float silu_f(float v) {
    return v * __builtin_amdgcn_rcpf(1.0f + __expf(-v));
}
__device__ __forceinline__ short f2bf(float f) {          // RNE (wprep only)
    unsigned u = __float_as_uint(f);
    unsigned r = u + 0x7fffu + ((u >> 16) & 1u);
    return (short)(r >> 16);
}
__device__ __forceinline__ float bf2f(short s) {
    return __uint_as_float(((unsigned)(unsigned short)s) << 16);
}

__device__ __forceinline__ unsigned cvt_pk_bf16(float a, float b) {
    __hip_bfloat162 h = __float22bfloat162_rn(float2{a, b});   // v_cvt_pk_bf16_f32
    return *reinterpret_cast<unsigned*>(&h);
}
// fp32x8 -> bf16 hi + lo residual, using packed cvt (RNE, bit-identical to f2bf)
__device__ __forceinline__ void split44(f32x4 a, f32x4 b, bf16x8& hi, bf16x8& lo) {
    float f[8] = {a[0], a[1], a[2], a[3], b[0], b[1], b[2], b[3]};
    u32x4 H, L;
    #pragma unroll
    for (int j = 0; j < 4; ++j) {
        const float f0 = f[2 * j], f1 = f[2 * j + 1];
        const unsigned h = cvt_pk_bf16(f0, f1);
        const float r0 = f0 - __uint_as_float(h << 16);
        const float r1 = f1 - __uint_as_float(h & 0xffff0000u);
        H[j] = h;
        L[j] = cvt_pk_bf16(r0, r1);
    }
    hi = __builtin_bit_cast(bf16x8, H);
    lo = __builtin_bit_cast(bf16x8, L);
}

__device__ __forceinline__ void gll16(const void* g, void* l) {
    __builtin_amdgcn_global_load_lds((const __attribute__((address_space(1))) void*)g,
                                     (__attribute__((address_space(3))) void*)l, 16, 0, 0);
}
__device__ __forceinline__ void stage16(const char* g, short* l, int lane, int wid) {
    #pragma unroll
    for (int i = 0; i < 4; ++i) {
        const int off = ((i * 4 + wid) << 10);
        gll16(g + off + lane * 16, (char*)l + off);
    }
}
__device__ __forceinline__ void stage8(const char* g, short* l, int lane, int wid) {
    #pragma unroll
    for (int i = 0; i < 2; ++i) {
        const int off = ((i * 4 + wid) << 10);
        gll16(g + off + lane * 16, (char*)l + off);
    }
}

template<int NF>
__device__ __forceinline__ void mfma_ks(bf16x8 ah, bf16x8 al, const short* slot,
                                        int acol, int kq, f32x4* acc) {
    #pragma unroll
    for (int n = 0; n < NF; ++n) {
        const int c = n * 16 + acol;
        const int x = (c >> 2) & 1;
        const int sw = (kq ^ (c & 3)) << 3;
        const bf16x8 bh = *(const bf16x8*)&slot[c * 64 + x * 32 + sw];
        const bf16x8 bl = *(const bf16x8*)&slot[c * 64 + (x ^ 1) * 32 + sw];
        acc[n] = __builtin_amdgcn_mfma_f32_16x16x32_bf16(ah, bh, acc[n], 0, 0, 0);
        acc[n] = __builtin_amdgcn_mfma_f32_16x16x32_bf16(al, bh, acc[n], 0, 0, 0);
        acc[n] = __builtin_amdgcn_mfma_f32_16x16x32_bf16(ah, bl, acc[n], 0, 0, 0);
    }
}
template<int NF>
__device__ __forceinline__ void gphase(f32x4 a0, f32x4 a1, const short* slot,
                                       int acol, int kq, f32x4* acc) {
    bf16x8 ah, al; split44(a0, a1, ah, al);
    mfma_ks<NF>(ah, al, slot, acol, kq, acc);
}
template<int NF>
__device__ __forceinline__ void tphase(const float* tl, int rowbase, int q,
                                       int kq, int acol, const short* slot, f32x4* acc) {
    const f32x4 ta = *(const f32x4*)&tl[rowbase + q * 32 + kq * 8];
    const f32x4 tb = *(const f32x4*)&tl[rowbase + q * 32 + kq * 8 + 4];
    bf16x8 ah, al; split44(ta, tb, ah, al);
    mfma_ks<NF>(ah, al, slot, acol, kq, acc);
}

__device__ __forceinline__ void tgemm4(const char* img, const char* imgnext,
                                       short* sA, short* sB, const float* tl, int rb,
                                       int kq, int acol, int lane, int wid, f32x4* acc)
{
    stage16(img + 16384, sB, lane, wid);
    tphase<8>(tl, rb, 0, kq, acol, sA, acc); __syncthreads();
    stage16(img + 32768, sA, lane, wid);
    tphase<8>(tl, rb, 1, kq, acol, sB, acc); __syncthreads();
    stage16(img + 49152, sB, lane, wid);
    tphase<8>(tl, rb, 2, kq, acol, sA, acc); __syncthreads();
    if (imgnext) stage16(imgnext, sA, lane, wid);
    tphase<8>(tl, rb, 3, kq, acol, sB, acc); __syncthreads();
}

#define TPITCH 132

// ---------------- weight pre-conversion -------------------------------------
struct WDesc { const float* src; char* dst; int K; int N; };
struct WPrepArgs { WDesc w[11]; };

__global__ void wprep_kernel(WPrepArgs args) {
    const WDesc d = args.w[blockIdx.y];
    const int h = blockIdx.x;
    if (h * 32 >= d.K) return;
    char* slab = d.dst + (size_t)h * d.N * 128;
    for (int idx = threadIdx.x; idx < d.N * 4; idx += 256) {
        const int c = idx >> 2, ch = idx & 3;
        bf16x8 hi, lo;
        #pragma unroll
        for (int j = 0; j < 8; ++j) {
            const float f = d.src[(size_t)(h * 32 + ch * 8 + j) * d.N + c];
            const short hb = f2bf(f);
            hi[j] = hb;
            lo[j] = f2bf(f - bf2f(hb));
        }
        const int x = (c >> 2) & 1;
        const int sw = (ch ^ (c & 3)) * 16;
        *(bf16x8*)(slab + c * 128 + x * 64 + sw)       = hi;
        *(bf16x8*)(slab + c * 128 + (x ^ 1) * 64 + sw) = lo;
    }
}

// ---------------- prologue / CSR --------------------------------------------

__global__ void rbf1_kernel(const float* __restrict__ rbf, const float* __restrict__ w_rbf1,
                            float* __restrict__ re1, int E) {
    const int i = blockIdx.x * 256 + threadIdx.x;
    const int e = i >> 3, p = i & 7;
    if (e < E) {
        float s = 0.f;
        #pragma unroll
        for (int q = 0; q < 6; ++q) s = fmaf(rbf[e * 6 + q], w_rbf1[q * 8 + p], s);
        re1[i] = s;
    }
}

__global__ void count_rank_kernel(const int* __restrict__ idx_ji, int* __restrict__ cnt,
                                  int* __restrict__ rank, int T) {
    const int i = (blockIdx.x * 256 + threadIdx.x) * 4;
    if (i + 3 < T) {
        const int4 j = *(const int4*)&idx_ji[i];
        int4 r;
        r.x = atomicAdd(&cnt[j.x], 1);
        r.y = atomicAdd(&cnt[j.y], 1);
        r.z = atomicAdd(&cnt[j.z], 1);
        r.w = atomicAdd(&cnt[j.w], 1);
        *(int4*)&rank[i] = r;
    } else {
        for (int k = i; k < T; ++k) rank[k] = atomicAdd(&cnt[idx_ji[k]], 1);
    }
}

__global__ void scan_partial_kernel(const int* __restrict__ cnt, int* __restrict__ partial, int E) {
    __shared__ int red[256];
    const int tid = threadIdx.x;
    const int base = blockIdx.x * 1024 + tid * 4;
    int s = 0;
    #pragma unroll
    for (int i = 0; i < 4; ++i) { const int g = base + i; if (g < E) s += cnt[g]; }
    red[tid] = s;
    __syncthreads();
    for (int off = 128; off > 0; off >>= 1) {
        if (tid < off) red[tid] += red[tid + off];
        __syncthreads();
    }
    if (tid == 0) partial[blockIdx.x] = red[0];
}

__global__ void scan_block_kernel(const int* __restrict__ partial, int* __restrict__ blockoff,
                                  int NB, int* offsets, int E) {
    __shared__ int red[256];
    const int tid = threadIdx.x;
    int v[4]; int s = 0;
    #pragma unroll
    for (int i = 0; i < 4; ++i) { const int g = tid * 4 + i; v[i] = (g < NB) ? partial[g] : 0; s += v[i]; }
    red[tid] = s;
    __syncthreads();
    for (int off = 1; off < 256; off <<= 1) {
        const int add = (tid >= off) ? red[tid - off] : 0;
        __syncthreads();
        red[tid] += add;
        __syncthreads();
    }
    int excl = (tid == 0) ? 0 : red[tid - 1];
    #pragma unroll
    for (int i = 0; i < 4; ++i) { const int g = tid * 4 + i; if (g < NB) blockoff[g] = excl; excl += v[i]; }
    if (tid == 255) offsets[E] = red[255];
}

__global__ void scan_final_kernel(const int* __restrict__ cnt, const int* __restrict__ blockoff,
                                  int* __restrict__ offsets, int E) {
    __shared__ int red[256];
    const int tid = threadIdx.x;
    const int base = blockIdx.x * 1024 + tid * 4;
    int v[4]; int s = 0;
    #pragma unroll
    for (int i = 0; i < 4; ++i) { const int g = base + i; v[i] = (g < E) ? cnt[g] : 0; s += v[i]; }
    red[tid] = s;
    __syncthreads();
    for (int off = 1; off < 256; off <<= 1) {
        const int add = (tid >= off) ? red[tid - off] : 0;
        __syncthreads();
        red[tid] += add;
        __syncthreads();
    }
    int run = blockoff[blockIdx.x] + ((tid == 0) ? 0 : red[tid - 1]);
    #pragma unroll
    for (int i = 0; i < 4; ++i) {
        const int g = base + i;
        if (g < E) offsets[g] = run;
        run += v[i];
    }
}

__launch_bounds__(256, 3)
__global__ void e1fill_kernel(const float* __restrict__ sbf, const float* __restrict__ w_sbf1,
                              const int* __restrict__ idx_ji, const int* __restrict__ idx_kj,
                              const int* __restrict__ rank, const int* __restrict__ offsets,
                              float* __restrict__ E1p, int* __restrict__ kjp, int T)
{
    __shared__ float s_lds[256 * 43];
    const int tid = threadIdx.x;
    const long long t0 = (long long)blockIdx.x * 256;
    const int nrow = min(256, (int)(T - t0));
    const int nel  = nrow * 42;
    const float* base = sbf + t0 * 42;

    for (int i = tid * 4; i + 3 < nel; i += 1024) {
        const float4 v = *(const float4*)&base[i];
        s_lds[(i + 0) + (i + 0) / 42] = v.x;
        s_lds[(i + 1) + (i + 1) / 42] = v.y;
        s_lds[(i + 2) + (i + 2) / 42] = v.z;
        s_lds[(i + 3) + (i + 3) / 42] = v.w;
    }
    const int tail0 = nel & ~3;
    if (tid < nel - tail0) { const int g = tail0 + tid; s_lds[g + g / 42] = base[g]; }
    __syncthreads();

    const int t = (int)t0 + tid;
    if (t >= T) return;
    const float* srow = &s_lds[tid * 43];
    float e1[8] = {0.f, 0.f, 0.f, 0.f, 0.f, 0.f, 0.f, 0.f};
    #pragma unroll
    for (int q = 0; q < 42; ++q) {
        const float s = srow[q];
        #pragma unroll
        for (int p = 0; p < 8; ++p) e1[p] = fmaf(s, w_sbf1[q * 8 + p], e1[p]);
    }
    const int ji  = idx_ji[t];
    const int pos = offsets[ji] + rank[t];
    *(float4*)&E1p[(size_t)pos * 8]     = *(float4*)&e1[0];
    *(float4*)&E1p[(size_t)pos * 8 + 4] = *(float4*)&e1[4];
    kjp[pos] = idx_kj[t];
}

__launch_bounds__(256, 4)
__global__ void gather_kernel(const float* __restrict__ E1p, const int* __restrict__ kjp,
                              const float* __restrict__ w_sbf2, const int* __restrict__ offsets,
                              const float* __restrict__ xkjd, float* __restrict__ agg, int E)
{
    const int tid  = threadIdx.x;
    const int lane = tid & 63;
    const int e    = blockIdx.x * 4 + (tid >> 6);

    float w2[8];
    #pragma unroll
    for (int p = 0; p < 8; ++p) w2[p] = w_sbf2[p * 64 + lane];

    if (e >= E) return;
    const int j0 = __builtin_amdgcn_readfirstlane(offsets[e]);
    const int j1 = __builtin_amdgcn_readfirstlane(offsets[e + 1]);

    float acc = 0.f;
    if (j0 < j1) {
        int kj = __builtin_amdgcn_readfirstlane(kjp[j0]);
        float4 ea = *(const float4*)&E1p[(size_t)j0 * 8];
        float4 eb = *(const float4*)&E1p[(size_t)j0 * 8 + 4];
        for (int j = j0; j < j1; ++j) {
            const float xv = xkjd[(size_t)kj * 64 + lane];
            int kn = 0; float4 ean = {}, ebn = {};
            if (j + 1 < j1) {
                kn  = __builtin_amdgcn_readfirstlane(kjp[j + 1]);
                ean = *(const float4*)&E1p[(size_t)(j + 1) * 8];
                ebn = *(const float4*)&E1p[(size_t)(j + 1) * 8 + 4];
            }
            float sv = ea.x * w2[0];
            sv = fmaf(ea.y, w2[1], sv);
            sv = fmaf(ea.z, w2[2], sv);
            sv = fmaf(ea.w, w2[3], sv);
            sv = fmaf(eb.x, w2[4], sv);
            sv = fmaf(eb.y, w2[5], sv);
            sv = fmaf(eb.z, w2[6], sv);
            sv = fmaf(eb.w, w2[7], sv);
            acc = fmaf(xv, sv, acc);
            kj = kn; ea = ean; eb = ebn;
        }
    }
    agg[(size_t)e * 64 + lane] = acc;
}

// ---------------- K1: W3 = silu((silu(x@w_kj+b)*rbf_e)@w_down) --------------
__launch_bounds__(256, 2)
__global__ void k1_kernel(const float* __restrict__ x, const char* __restrict__ wkj_i,
                          const float* __restrict__ b_kj, const float* __restrict__ re1,
                          const float* __restrict__ w_rbf2, const char* __restrict__ wdn_i,
                          float* __restrict__ W3, int E)
{
    __shared__ short slotA[8192], slotB[8192];
    __shared__ float t_lds[64 * TPITCH];
    __shared__ float w2_lds[8 * 128];
    const int tid = threadIdx.x, lane = tid & 63, wid = tid >> 6;
    const int acol = lane & 15, kq = lane >> 4;
    const int rowW = blockIdx.x * 64 + wid * 16;
    const int arow = rowW + acol;
    const bool av = arow < E;

    stage16(wkj_i, slotA, lane, wid);
    const float* xr = x + (size_t)arow * 128;
    f32x4 a[4][2];
    #pragma unroll
    for (int ks = 0; ks < 4; ++ks) {
        a[ks][0] = f32x4{0.f, 0.f, 0.f, 0.f}; a[ks][1] = f32x4{0.f, 0.f, 0.f, 0.f};
        if (av) { a[ks][0] = *(const f32x4*)&xr[ks * 32 + kq * 8];
                  a[ks][1] = *(const f32x4*)&xr[ks * 32 + kq * 8 + 4]; }
    }
    float bv[8];
    #pragma unroll
    for (int n = 0; n < 8; ++n) bv[n] = b_kj[n * 16 + acol];
    f32x4 e1a[4], e1b[4];
    #pragma unroll
    for (int r = 0; r < 4; ++r) {
        const int ge = rowW + kq * 4 + r;
        e1a[r] = f32x4{0.f, 0.f, 0.f, 0.f}; e1b[r] = f32x4{0.f, 0.f, 0.f, 0.f};
        if (ge < E) { e1a[r] = *(const f32x4*)&re1[(size_t)ge * 8];
                      e1b[r] = *(const f32x4*)&re1[(size_t)ge * 8 + 4]; }
    }
    for (int i = tid; i < 1024; i += 256) w2_lds[i] = w_rbf2[i];
    __syncthreads();

    f32x4 acc[8];
    #pragma unroll
    for (int n = 0; n < 8; ++n) acc[n] = f32x4{0.f, 0.f, 0.f, 0.f};

    stage16(wkj_i + 16384, slotB, lane, wid);
    gphase<8>(a[0][0], a[0][1], slotA, acol, kq, acc); __syncthreads();
    stage16(wkj_i + 32768, slotA, lane, wid);
    gphase<8>(a[1][0], a[1][1], slotB, acol, kq, acc); __syncthreads();
    stage16(wkj_i + 49152, slotB, lane, wid);
    gphase<8>(a[2][0], a[2][1], slotA, acol, kq, acc); __syncthreads();
    stage8(wdn_i, slotA, lane, wid);
    gphase<8>(a[3][0], a[3][1], slotB, acol, kq, acc); __syncthreads();

    #pragma unroll
    for (int n = 0; n < 8; ++n) {
        const int c = n * 16 + acol;
        float w2c[8];
        #pragma unroll
        for (int p = 0; p < 8; ++p) w2c[p] = w2_lds[p * 128 + c];
        #pragma unroll
        for (int r = 0; r < 4; ++r) {
            float s = e1a[r][0] * w2c[0];
            s = fmaf(e1a[r][1], w2c[1], s);
            s = fmaf(e1a[r][2], w2c[2], s);
            s = fmaf(e1a[r][3], w2c[3], s);
            s = fmaf(e1b[r][0], w2c[4], s);
            s = fmaf(e1b[r][1], w2c[5], s);
            s = fmaf(e1b[r][2], w2c[6], s);
            s = fmaf(e1b[r][3], w2c[7], s);
            t_lds[(wid * 16 + kq * 4 + r) * TPITCH + c] = silu_f(acc[n][r] + bv[n]) * s;
        }
    }
    __syncthreads();

    f32x4 acc2[4];
    #pragma unroll
    for (int n = 0; n < 4; ++n) acc2[n] = f32x4{0.f, 0.f, 0.f, 0.f};
    const int rb = (wid * 16 + acol) * TPITCH;

    stage8(wdn_i + 8192, slotB, lane, wid);
    tphase<4>(t_lds, rb, 0, kq, acol, slotA, acc2); __syncthreads();
    stage8(wdn_i + 16384, slotA, lane, wid);
    tphase<4>(t_lds, rb, 1, kq, acol, slotB, acc2); __syncthreads();
    stage8(wdn_i + 24576, slotB, lane, wid);
    tphase<4>(t_lds, rb, 2, kq, acol, slotA, acc2); __syncthreads();
    tphase<4>(t_lds, rb, 3, kq, acol, slotB, acc2);

    #pragma unroll
    for (int n = 0; n < 4; ++n) {
        const int c = n * 16 + acol;
        #pragma unroll
        for (int r = 0; r < 4; ++r) {
            const int ge = rowW + kq * 4 + r;
            if (ge < E) W3[(size_t)ge * 64 + c] = silu_f(acc2[n][r]);
        }
    }
}

// ---------------- kbig: h0 -> res1 -> w_bs+skip -> res2 -> res3 (9 GEMMs) ---
struct KBigArgs {
    const float* x; const float* W4; float* out;
    const char *wji, *wup, *r1w1, *r1w2, *wbs, *r2w1, *r2w2, *r3w1, *r3w2;
    const float *bji, *r1b1, *r1b2, *bbs, *r2b1, *r2b2, *r3b1, *r3b2;
    int E;
};

__launch_bounds__(256, 2)
__global__ void kbig_kernel(KBigArgs A_)
{
    __shared__ short slotA[8192], slotB[8192];
    __shared__ float t_lds[64 * TPITCH];
    const int tid = threadIdx.x, lane = tid & 63, wid = tid >> 6;
    const int acol = lane & 15, kq = lane >> 4;
    const int rowW = blockIdx.x * 64 + wid * 16;
    const int arow = rowW + acol;
    const int E = A_.E;
    const bool av = arow < E;
    const int rb = (wid * 16 + acol) * TPITCH;

    stage16(A_.wji, slotA, lane, wid);

    const float* xr = A_.x + (size_t)arow * 128;
    const float* wr = A_.W4 + (size_t)arow * 64;
    f32x4 a[4][2], u[2][2];
    #pragma unroll
    for (int ks = 0; ks < 4; ++ks) {
        a[ks][0] = f32x4{0.f, 0.f, 0.f, 0.f}; a[ks][1] = f32x4{0.f, 0.f, 0.f, 0.f};
        if (av) { a[ks][0] = *(const f32x4*)&xr[ks * 32 + kq * 8];
                  a[ks][1] = *(const f32x4*)&xr[ks * 32 + kq * 8 + 4]; }
    }
    #pragma unroll
    for (int ks = 0; ks < 2; ++ks) {
        u[ks][0] = f32x4{0.f, 0.f, 0.f, 0.f}; u[ks][1] = f32x4{0.f, 0.f, 0.f, 0.f};
        if (av) { u[ks][0] = *(const f32x4*)&wr[ks * 32 + kq * 8];
                  u[ks][1] = *(const f32x4*)&wr[ks * 32 + kq * 8 + 4]; }
    }
    __syncthreads();

    f32x4 acc[8];
    #pragma unroll
    for (int n = 0; n < 8; ++n) acc[n] = f32x4{0.f, 0.f, 0.f, 0.f};

    // GEMM1: x @ w_ji
    stage16(A_.wji + 16384, slotB, lane, wid);
    gphase<8>(a[0][0], a[0][1], slotA, acol, kq, acc); __syncthreads();
    stage16(A_.wji + 32768, slotA, lane, wid);
    gphase<8>(a[1][0], a[1][1], slotB, acol, kq, acc); __syncthreads();
    stage16(A_.wji + 49152, slotB, lane, wid);
    gphase<8>(a[2][0], a[2][1], slotA, acol, kq, acc); __syncthreads();
    stage16(A_.wup, slotA, lane, wid);
    gphase<8>(a[3][0], a[3][1], slotB, acol, kq, acc); __syncthreads();

    float res[8][4];
    #pragma unroll
    for (int n = 0; n < 8; ++n) {
        const float bv = A_.bji[n * 16 + acol];
        #pragma unroll
        for (int r = 0; r < 4; ++r) { res[n][r] = silu_f(acc[n][r] + bv); acc[n][r] = 0.f; }
    }

    // GEMM2: W4 @ w_up (K=64)
    stage16(A_.wup + 16384, slotB, lane, wid);
    gphase<8>(u[0][0], u[0][1], slotA, acol, kq, acc); __syncthreads();
    stage16(A_.r1w1, slotA, lane, wid);
    gphase<8>(u[1][0], u[1][1], slotB, acol, kq, acc); __syncthreads();

    #pragma unroll
    for (int n = 0; n < 8; ++n) {
        const int c = n * 16 + acol;
        #pragma unroll
        for (int r = 0; r < 4; ++r) {
            res[n][r] += silu_f(acc[n][r]);                     // h0
            t_lds[(wid * 16 + kq * 4 + r) * TPITCH + c] = res[n][r];
            acc[n][r] = 0.f;
        }
    }
    __syncthreads();

    // GEMM3: h0 @ r1w1 -> t1
    tgemm4(A_.r1w1, A_.r1w2, slotA, slotB, t_lds, rb, kq, acol, lane, wid, acc);
    #pragma unroll
    for (int n = 0; n < 8; ++n) {
        const float bv = A_.r1b1[n * 16 + acol];
        const int c = n * 16 + acol;
        #pragma unroll
        for (int r = 0; r < 4; ++r) {
            t_lds[(wid * 16 + kq * 4 + r) * TPITCH + c] = silu_f(acc[n][r] + bv);
            acc[n][r] = 0.f;
        }
    }
    __syncthreads();

    // GEMM4: t1 @ r1w2 -> t2 = h0 + silu(.)
    tgemm4(A_.r1w2, A_.wbs, slotA, slotB, t_lds, rb, kq, acol, lane, wid, acc);
    #pragma unroll
    for (int n = 0; n < 8; ++n) {
        const float bv = A_.r1b2[n * 16 + acol];
        const int c = n * 16 + acol;
        #pragma unroll
        for (int r = 0; r < 4; ++r) {
            t_lds[(wid * 16 + kq * 4 + r) * TPITCH + c] = res[n][r] + silu_f(acc[n][r] + bv);
            acc[n][r] = 0.f;
        }
    }
    __syncthreads();

    // GEMM5: t2 @ w_bs -> h2 = silu(.) + x
    tgemm4(A_.wbs, A_.r2w1, slotA, slotB, t_lds, rb, kq, acol, lane, wid, acc);
    #pragma unroll
    for (int n = 0; n < 8; ++n) {
        const float bv = A_.bbs[n * 16 + acol];
        const int c = n * 16 + acol;
        #pragma unroll
        for (int r = 0; r < 4; ++r) {
            const int ge = rowW + kq * 4 + r;
            const float xv = (ge < E) ? A_.x[(size_t)ge * 128 + c] : 0.f;
            res[n][r] = silu_f(acc[n][r] + bv) + xv;            // h2
            t_lds[(wid * 16 + kq * 4 + r) * TPITCH + c] = res[n][r];
            acc[n][r] = 0.f;
        }
    }
    __syncthreads();

    // GEMM6: h2 @ r2w1 -> t3
    tgemm4(A_.r2w1, A_.r2w2, slotA, slotB, t_lds, rb, kq, acol, lane, wid, acc);
    #pragma unroll
    for (int n = 0; n < 8; ++n) {
        const float bv = A_.r2b1[n * 16 + acol];
        const int c = n * 16 + acol;
        #pragma unroll
        for (int r = 0; r < 4; ++r) {
            t_lds[(wid * 16 + kq * 4 + r) * TPITCH + c] = silu_f(acc[n][r] + bv);
            acc[n][r] = 0.f;
        }
    }
    __syncthreads();

    // GEMM7: t3 @ r2w2 -> h3 = h2 + silu(.)
    tgemm4(A_.r2w2, A_.r3w1, slotA, slotB, t_lds, rb, kq, acol, lane, wid, acc);
    #pragma unroll
    for (int n = 0; n < 8; ++n) {
        const float bv = A_.r2b2[n * 16 + acol];
        const int c = n * 16 + acol;
        #pragma unroll
        for (int r = 0; r < 4; ++r) {
            res[n][r] += silu_f(acc[n][r] + bv);                // h3
            t_lds[(wid * 16 + kq * 4 + r) * TPITCH + c] = res[n][r];
            acc[n][r] = 0.f;
        }
    }
    __syncthreads();

    // GEMM8: h3 @ r3w1 -> t4
    tgemm4(A_.r3w1, A_.r3w2, slotA, slotB, t_lds, rb, kq, acol, lane, wid, acc);
    #pragma unroll
    for (int n = 0; n < 8; ++n) {
        const float bv = A_.r3b1[n * 16 + acol];
        const int c = n * 16 + acol;
        #pragma unroll
        for (int r = 0; r < 4; ++r) {
            t_lds[(wid * 16 + kq * 4 + r) * TPITCH + c] = silu_f(acc[n][r] + bv);
            acc[n][r] = 0.f;
        }
    }
    __syncthreads();

    // GEMM9: t4 @ r3w2 -> out = h3 + silu(.)
    tgemm4(A_.r3w2, nullptr, slotA, slotB, t_lds, rb, kq, acol, lane, wid, acc);
    #pragma unroll
    for (int n = 0; n < 8; ++n) {
        const float bv = A_.r3b2[n * 16 + acol];
        const int c = n * 16 + acol;
        #pragma unroll
        for (int r = 0; r < 4; ++r) {
            const int ge = rowW + kq * 4 + r;
            if (ge < E)
                A_.out[(size_t)ge * 128 + c] = res[n][r] + silu_f(acc[n][r] + bv);
        }
    }
}

// ---------------------------------------------------------------------------

extern "C" void kernel_launch(void* const* d_in, const int* in_sizes, int n_in,
                              void* d_out, int out_size, void* d_ws, size_t ws_size,
                              hipStream_t stream)
{
    const float* x      = (const float*)d_in[0];
    const float* rbf    = (const float*)d_in[1];
    const float* sbf    = (const float*)d_in[2];
    const int*   idx_kj = (const int*)d_in[3];
    const int*   idx_ji = (const int*)d_in[4];
    const float* w_rbf1 = (const float*)d_in[5];
    const float* w_rbf2 = (const float*)d_in[6];
    const float* w_sbf1 = (const float*)d_in[7];
    const float* w_sbf2 = (const float*)d_in[8];
    const float* w_kj   = (const float*)d_in[9];
    const float* b_kj   = (const float*)d_in[10];
    const float* w_ji   = (const float*)d_in[11];
    const float* b_ji   = (const float*)d_in[12];
    const float* w_down = (const float*)d_in[13];
    const float* w_up   = (const float*)d_in[14];
    const float* r1w1   = (const float*)d_in[15];
    const float* r1b1   = (const float*)d_in[16];
    const float* r1w2   = (const float*)d_in[17];
    const float* r1b2   = (const float*)d_in[18];
    const float* w_bs   = (const float*)d_in[19];
    const float* b_bs   = (const float*)d_in[20];
    const float* r2w1   = (const float*)d_in[21];
    const float* r2b1   = (const float*)d_in[22];
    const float* r2w2   = (const float*)d_in[23];
    const float* r2b2   = (const float*)d_in[24];
    const float* r3w1   = (const float*)d_in[25];
    const float* r3b1   = (const float*)d_in[26];
    const float* r3w2   = (const float*)d_in[27];
    const float* r3b2   = (const float*)d_in[28];

    const int E = in_sizes[0] / 128;
    const int T = in_sizes[2] / 42;

    float* OUT = (float*)d_out;
    float* W3  = (float*)((char*)d_ws + (size_t)E * 128 * 4);         // [E,64]
    float* W4  = (float*)((char*)d_ws + (size_t)E * 128 * 4
                                      + (size_t)E * 64 * 4);          // [E,64]

    int*   cnt      = (int*)d_ws;                            // [E]
    int*   offsets  = cnt + (E + 64);                        // [E+1]
    int*   partial  = offsets + (E + 64);                    // [<=1024]
    int*   blockoff = partial + 1024;                        // [<=1024]
    float* E1p      = (float*)((char*)d_ws + (4u << 20));    // [T,8]   96 MB
    int*   kjp      = (int*)((char*)d_ws + (102u << 20));    // [T]     12 MB
    float* re1      = (float*)((char*)d_ws + (116u << 20));  // [E,8]  9.6 MB
    char*  wimg     = (char*)d_ws + (130u << 20);            // 640 KB
    int*   rank     = (int*)((char*)d_ws + (134u << 20));    // [T]     12 MB

    char* wkj_i  = wimg;
    char* wji_i  = wimg + 65536;
    char* wdn_i  = wimg + 131072;
    char* wup_i  = wimg + 163840;
    char* r1w1_i = wimg + 196608;
    char* r1w2_i = wimg + 262144;
    char* wbs_i  = wimg + 327680;
    char* r2w1_i = wimg + 393216;
    char* r2w2_i = wimg + 458752;
    char* r3w1_i = wimg + 524288;
    char* r3w2_i = wimg + 589824;

    WPrepArgs pa;
    pa.w[0]  = {w_kj,   wkj_i,  128, 128};
    pa.w[1]  = {w_ji,   wji_i,  128, 128};
    pa.w[2]  = {w_down, wdn_i,  128,  64};
    pa.w[3]  = {w_up,   wup_i,   64, 128};
    pa.w[4]  = {r1w1,   r1w1_i, 128, 128};
    pa.w[5]  = {r1w2,   r1w2_i, 128, 128};
    pa.w[6]  = {w_bs,   wbs_i,  128, 128};
    pa.w[7]  = {r2w1,   r2w1_i, 128, 128};
    pa.w[8]  = {r2w2,   r2w2_i, 128, 128};
    pa.w[9]  = {r3w1,   r3w1_i, 128, 128};
    pa.w[10] = {r3w2,   r3w2_i, 128, 128};

    const dim3 b256(256);
    const int gB  = (E + 63) / 64;
    const int gT  = (T + 255) / 256;
    const int gT4 = (T + 1023) / 1024;
    const int NB  = (E + 1023) / 1024;
    const int gE4 = (E + 3) / 4;
    const int gR  = (E * 8 + 255) / 256;

    wprep_kernel<<<dim3(4, 11), b256, 0, stream>>>(pa);
    rbf1_kernel<<<gR, b256, 0, stream>>>(rbf, w_rbf1, re1, E);
    hipMemsetAsync(cnt, 0, (size_t)E * 4, stream);
    count_rank_kernel<<<gT4, b256, 0, stream>>>(idx_ji, cnt, rank, T);
    scan_partial_kernel<<<NB, b256, 0, stream>>>(cnt, partial, E);
    scan_block_kernel<<<1, b256, 0, stream>>>(partial, blockoff, NB, offsets, E);
    scan_final_kernel<<<NB, b256, 0, stream>>>(cnt, blockoff, offsets, E);
    e1fill_kernel<<<gT, b256, 0, stream>>>(sbf, w_sbf1, idx_ji, idx_kj, rank, offsets, E1p, kjp, T);

    k1_kernel<<<gB, b256, 0, stream>>>(x, wkj_i, b_kj, re1, w_rbf2, wdn_i, W3, E);
    gather_kernel<<<gE4, b256, 0, stream>>>(E1p, kjp, w_sbf2, offsets, W3, W4, E);

    KBigArgs ka;
    ka.x = x; ka.W4 = W4; ka.out = OUT;
    ka.wji = wji_i; ka.wup = wup_i; ka.r1w1 = r1w1_i; ka.r1w2 = r1w2_i; ka.wbs = wbs_i;
    ka.r2w1 = r2w1_i; ka.r2w2 = r2w2_i; ka.r3w1 = r3w1_i; ka.r3w2 = r3w2_i;
    ka.bji = b_ji; ka.r1b1 = r1b1; ka.r1b2 = r1b2; ka.bbs = b_bs;
    ka.r2b1 = r2b1; ka.r2b2 = r2b2; ka.r3b1 = r3b1; ka.r3b2 = r3b2;
    ka.E = E;
    kbig_kernel<<<gB, b256, 0, stream>>>(ka);
}